// Round 6
// baseline (844.070 us; speedup 1.0000x reference)
//
#include <hip/hip_runtime.h>
#include <hip/hip_bf16.h>

#define NEG_SLOPE 0.2f
#define SB 256          // bucket-scatter workgroups (fused into gemm kernel)
#define HWG 384         // histogram workgroups

typedef __attribute__((ext_vector_type(8))) short bfrag;
typedef __attribute__((ext_vector_type(4))) float f32x4;
typedef unsigned short ushort_t;

__device__ __forceinline__ float lrelu(float x) {
    return x >= 0.0f ? x : NEG_SLOPE * x;
}
__device__ __forceinline__ unsigned short f2bf(float f) {  // round-to-nearest-even
    unsigned int u = __float_as_uint(f);
    u += 0x7fffu + ((u >> 16) & 1u);
    return (unsigned short)(u >> 16);
}
__device__ __forceinline__ float bf2f(unsigned short h) {
    return __uint_as_float(((unsigned int)h) << 16);
}
__device__ __forceinline__ float u2lo(unsigned int u) {
    return __uint_as_float(u << 16);
}
__device__ __forceinline__ float u2hi(unsigned int u) {
    return __uint_as_float(u & 0xffff0000u);
}

// ============ K1: bucket histogram + W1 split-bf16 prep (fused) ============
__global__ __launch_bounds__(256) void hist_prep_kernel(
    const int* __restrict__ edst, int* __restrict__ bcnt, int E, int NB,
    const float* __restrict__ W1, ushort_t* __restrict__ Whi,
    ushort_t* __restrict__ Wlo) {
    if (blockIdx.x < 128) {
        int t = blockIdx.x * 256 + threadIdx.x;  // 32768
        int k = t >> 6, c = t & 63;
        float w = W1[t];
        unsigned short hi = f2bf(w);
        float rem = w - bf2f(hi);
        int dst = (k >> 7) * 8192 + c * 128 + (k & 127);
        Whi[dst] = hi;
        Wlo[dst] = f2bf(rem);
        return;
    }
    __shared__ int hist[512];
    int tid = threadIdx.x;
    for (int i = tid; i < NB; i += 256) hist[i] = 0;
    __syncthreads();
    int wg = blockIdx.x - 128;
    int CH = (E + HWG - 1) / HWG;
    int st = wg * CH, en = min(st + CH, E);
    for (int i = st + tid; i < en; i += 256)
        atomicAdd(&hist[edst[i] >> 8], 1);
    __syncthreads();
    for (int i = tid; i < NB; i += 256)
        if (hist[i] > 0) atomicAdd(&bcnt[i], hist[i]);
}

// ============ K2: bucket exclusive scan (one WG) ============
__global__ __launch_bounds__(512) void bscan_kernel(
    const int* __restrict__ bcnt, int* __restrict__ boff, int* __restrict__ bcur,
    int* __restrict__ csr_off, int NB, int N, int E) {
    __shared__ int s[512];
    int t = threadIdx.x;
    int v = (t < NB) ? bcnt[t] : 0;
    s[t] = v;
    __syncthreads();
    for (int off = 1; off < 512; off <<= 1) {
        int tv = (t >= off) ? s[t - off] : 0;
        __syncthreads();
        s[t] += tv;
        __syncthreads();
    }
    if (t < NB) {
        int o = s[t] - v;
        boff[t] = o;
        bcur[t] = o;
    }
    if (t == 0) {
        boff[NB] = E;
        csr_off[N] = E;
    }
}

// ============ K3: fused GEMM1 + bucket scatter + attention coeffs ============
// blocks [0,SB): scatter edges into bucket-contiguous ebuf (int2 {src,dst}).
// blocks [SB,...): MFMA gemm. ALL of W (hi+lo, 128 KB) staged into LDS ONCE
// per block (XOR-swizzled, conflict-free), then 16 waves each own a 16-row
// tile — zero barriers in the K loop, W reused 16x per block.
__global__ __launch_bounds__(1024) void gemm_bscatter_kernel(
    const float* __restrict__ x, const ushort_t* __restrict__ Whi,
    const ushort_t* __restrict__ Wlo, ushort_t* __restrict__ h1b, int n,
    const int* __restrict__ esrc, const int* __restrict__ edst,
    int* __restrict__ bcur, int2* __restrict__ ebuf, int E, int NB,
    const float* __restrict__ a_src1, const float* __restrict__ a_dst1,
    float* __restrict__ as1, float* __restrict__ ad1) {
    __shared__ __align__(16) ushort_t Wh[32768];   // 64 KB: [p][row][k] swizzled
    __shared__ __align__(16) ushort_t Wl[32768];   // 64 KB
    const int tid = threadIdx.x;   // 0..1023

    if (blockIdx.x < SB) {
        // ---- bucket scatter (uses Wh as int scratch) ----
        int* hist = (int*)Wh;
        int* base = hist + 512;
        int* rank = hist + 1024;
        for (int i = tid; i < NB; i += 1024) { hist[i] = 0; rank[i] = 0; }
        __syncthreads();
        int CH = (E + SB - 1) / SB;
        int st = blockIdx.x * CH, en = min(st + CH, E);
        for (int i = st + tid; i < en; i += 1024)
            atomicAdd(&hist[edst[i] >> 8], 1);
        __syncthreads();
        for (int b = tid; b < NB; b += 1024)
            if (hist[b] > 0) base[b] = atomicAdd(&bcur[b], hist[b]);
        __syncthreads();
        for (int i = st + tid; i < en; i += 1024) {
            int d = edst[i], s = esrc[i];
            int b = d >> 8;
            int r = atomicAdd(&rank[b], 1);
            ebuf[base[b] + r] = make_int2(s, d);
        }
        return;
    }

    // ---- stage all of W into LDS, swizzled (once per block) ----
    // global Whi layout: idx = p*8192 + row*128 + k ; LDS ushort idx ^= (row&7)<<3
    #pragma unroll
    for (int i = 0; i < 4; i++) {
        int lin = (tid + i * 1024) * 8;
        int row = (lin >> 7) & 63;
        int swz = lin ^ ((row & 7) << 3);
        *(bfrag*)&Wh[swz] = *(const bfrag*)&Whi[lin];
        *(bfrag*)&Wl[swz] = *(const bfrag*)&Wlo[lin];
    }
    __syncthreads();

    const int lane = tid & 63;
    const int wave = tid >> 6;      // 0..15
    const int l15 = lane & 15;
    const int lq = lane >> 4;
    const int r7s = (l15 & 7) << 3; // read-side swizzle (ushort units)

    const int ntiles = (n + 15) >> 4;
    const int tstride = (gridDim.x - SB) * 16;

    for (int tile = (blockIdx.x - SB) * 16 + wave; tile < ntiles; tile += tstride) {
        const int wb = tile * 16;
        f32x4 acc[4];
        #pragma unroll
        for (int t = 0; t < 4; t++) acc[t] = (f32x4){0.f, 0.f, 0.f, 0.f};

        const int arow = min(wb + l15, n - 1);
        const float* xr = x + (size_t)arow * 512;

        #pragma unroll
        for (int p = 0; p < 4; p++) {
            #pragma unroll
            for (int step = 0; step < 4; step++) {
                int kloc = step * 32 + lq * 8;
                int kb = p * 128 + kloc;
                float4 v0 = *(const float4*)&xr[kb];
                float4 v1 = *(const float4*)&xr[kb + 4];
                float xf[8] = {v0.x, v0.y, v0.z, v0.w, v1.x, v1.y, v1.z, v1.w};
                bfrag ah, al;
                #pragma unroll
                for (int j = 0; j < 8; j++) {
                    unsigned short hi = f2bf(xf[j]);
                    float rem = xf[j] - bf2f(hi);
                    ah[j] = (short)hi;
                    al[j] = (short)f2bf(rem);
                }
                #pragma unroll
                for (int t = 0; t < 4; t++) {
                    int nrow = t * 16 + l15;
                    int bidx = ((p * 64 + nrow) * 128 + kloc) ^ r7s;
                    bfrag bh = *(const bfrag*)&Wh[bidx];
                    bfrag bl = *(const bfrag*)&Wl[bidx];
                    acc[t] = __builtin_amdgcn_mfma_f32_16x16x32_bf16(al, bh, acc[t], 0, 0, 0);
                    acc[t] = __builtin_amdgcn_mfma_f32_16x16x32_bf16(ah, bl, acc[t], 0, 0, 0);
                    acc[t] = __builtin_amdgcn_mfma_f32_16x16x32_bf16(ah, bh, acc[t], 0, 0, 0);
                }
            }
        }
        // ---- h1b write (bf16 rows, 128 B line-aligned) ----
        #pragma unroll
        for (int t = 0; t < 4; t++) {
            #pragma unroll
            for (int reg = 0; reg < 4; reg++) {
                int grow = wb + lq * 4 + reg;
                if (grow < n) h1b[(size_t)grow * 64 + t * 16 + l15] = f2bf(acc[t][reg]);
            }
        }
        // ---- attention coefficients from fp32 accumulators ----
        const int j7 = l15 & 7;
        const int wrow = wb + lq * 4 + (j7 & 3);
        #pragma unroll
        for (int t = 0; t < 4; t++) {
            int cidx = t * 16 + l15;
            float cs = a_src1[cidx];
            float cd = a_dst1[cidx];
            float ps0 = acc[t][0] * cs, ps1 = acc[t][1] * cs;
            float ps2 = acc[t][2] * cs, ps3 = acc[t][3] * cs;
            float pd0 = acc[t][0] * cd, pd1 = acc[t][1] * cd;
            float pd2 = acc[t][2] * cd, pd3 = acc[t][3] * cd;
            #pragma unroll
            for (int off = 1; off < 8; off <<= 1) {
                ps0 += __shfl_xor(ps0, off);
                ps1 += __shfl_xor(ps1, off);
                ps2 += __shfl_xor(ps2, off);
                ps3 += __shfl_xor(ps3, off);
                pd0 += __shfl_xor(pd0, off);
                pd1 += __shfl_xor(pd1, off);
                pd2 += __shfl_xor(pd2, off);
                pd3 += __shfl_xor(pd3, off);
            }
            int h = (t << 1) | (l15 >> 3);
            if (wrow < n) {
                if (j7 < 4) {
                    float sv = j7 == 0 ? ps0 : j7 == 1 ? ps1 : j7 == 2 ? ps2 : ps3;
                    as1[wrow * 8 + h] = sv;
                } else {
                    float dv = j7 == 4 ? pd0 : j7 == 5 ? pd1 : j7 == 6 ? pd2 : pd3;
                    ad1[wrow * 8 + h] = dv;
                }
            }
        }
    }
}

// ============ K4: per-bucket CSR finalize ============
__global__ __launch_bounds__(256) void finalize_kernel(
    const int* __restrict__ boff, const int2* __restrict__ ebuf,
    int* __restrict__ csr_off, int* __restrict__ col, int N, int NB) {
    int tid = threadIdx.x;
    int b = blockIdx.x;
    __shared__ int cnt[256];
    __shared__ int cur[256];
    __shared__ int sc[256];
    cnt[tid] = 0;
    __syncthreads();
    int st = boff[b], en = boff[b + 1];
    for (int i = st + tid; i < en; i += 256)
        atomicAdd(&cnt[ebuf[i].y & 255], 1);
    __syncthreads();
    int v = cnt[tid];
    sc[tid] = v;
    __syncthreads();
    for (int off = 1; off < 256; off <<= 1) {
        int tv = (tid >= off) ? sc[tid - off] : 0;
        __syncthreads();
        sc[tid] += tv;
        __syncthreads();
    }
    int dbase = b << 8;
    int nd = min(256, N - dbase);
    int o = st + sc[tid] - v;   // exclusive
    if (tid < nd) {
        csr_off[dbase + tid] = o;
        cur[tid] = o;
    }
    __syncthreads();
    for (int i = st + tid; i < en; i += 256) {
        int2 p = ebuf[i];
        int r = atomicAdd(&cur[p.y & 255], 1);
        col[r] = p.x;
    }
}

// ============ agg1 + fused lin2 ============
__global__ __launch_bounds__(256) void agg1_kernel(
    const int* __restrict__ csr_off, const int* __restrict__ col,
    const ushort_t* __restrict__ h1b, const float* __restrict__ as1,
    const float* __restrict__ ad1,
    const float* __restrict__ b1, const float* __restrict__ W2,
    const float* __restrict__ a_src2, const float* __restrict__ a_dst2,
    float* __restrict__ g2, float* __restrict__ ad2, int n) {
    int d = blockIdx.x * 8 + (threadIdx.x >> 5);
    if (d >= n) return;
    int c = threadIdx.x & 31;
    int hd = c >> 2;
    const ushort_t* myrow = h1b + (size_t)d * 64;
    float adh = ad1[d * 8 + hd];
    float asd = as1[d * 8 + hd];
    float p0 = __expf(lrelu(asd + adh));
    unsigned int u = *(const unsigned int*)(myrow + c * 2);
    float denom = p0;
    float acc0 = p0 * u2lo(u);
    float acc1 = p0 * u2hi(u);
    int st = csr_off[d], en = csr_off[d + 1];
    int e = st;
    for (; e + 4 <= en; e += 4) {
        int s0 = col[e], s1 = col[e + 1], s2 = col[e + 2], s3 = col[e + 3];
        const ushort_t* r0 = h1b + (size_t)s0 * 64;
        const ushort_t* r1 = h1b + (size_t)s1 * 64;
        const ushort_t* r2 = h1b + (size_t)s2 * 64;
        const ushort_t* r3 = h1b + (size_t)s3 * 64;
        float a0 = as1[s0 * 8 + hd];
        float a1 = as1[s1 * 8 + hd];
        float a2 = as1[s2 * 8 + hd];
        float a3 = as1[s3 * 8 + hd];
        unsigned int u0 = *(const unsigned int*)(r0 + c * 2);
        unsigned int u1 = *(const unsigned int*)(r1 + c * 2);
        unsigned int u2 = *(const unsigned int*)(r2 + c * 2);
        unsigned int u3 = *(const unsigned int*)(r3 + c * 2);
        float q0 = __expf(lrelu(a0 + adh));
        float q1 = __expf(lrelu(a1 + adh));
        float q2 = __expf(lrelu(a2 + adh));
        float q3 = __expf(lrelu(a3 + adh));
        denom += (q0 + q1) + (q2 + q3);
        acc0 = fmaf(q0, u2lo(u0), acc0);
        acc1 = fmaf(q0, u2hi(u0), acc1);
        acc0 = fmaf(q1, u2lo(u1), acc0);
        acc1 = fmaf(q1, u2hi(u1), acc1);
        acc0 = fmaf(q2, u2lo(u2), acc0);
        acc1 = fmaf(q2, u2hi(u2), acc1);
        acc0 = fmaf(q3, u2lo(u3), acc0);
        acc1 = fmaf(q3, u2hi(u3), acc1);
    }
    for (; e < en; ++e) {
        int s0 = col[e];
        const ushort_t* r0 = h1b + (size_t)s0 * 64;
        float a0 = as1[s0 * 8 + hd];
        unsigned int u0 = *(const unsigned int*)(r0 + c * 2);
        float q0 = __expf(lrelu(a0 + adh));
        denom += q0;
        acc0 = fmaf(q0, u2lo(u0), acc0);
        acc1 = fmaf(q0, u2hi(u0), acc1);
    }
    float v0 = acc0 / denom + b1[2 * c];
    float v1 = acc1 / denom + b1[2 * c + 1];
    float h0 = v0 > 0.f ? v0 : (__expf(v0) - 1.f);
    float h1v = v1 > 0.f ? v1 : (__expf(v1) - 1.f);
    float g[7];
    #pragma unroll
    for (int j = 0; j < 7; j++) {
        float t = fmaf(h0, W2[(2 * c) * 7 + j], h1v * W2[(2 * c + 1) * 7 + j]);
        #pragma unroll
        for (int off = 1; off < 32; off <<= 1) t += __shfl_xor(t, off);
        g[j] = t;
    }
    float sa = 0.f, da = 0.f;
    #pragma unroll
    for (int j = 0; j < 7; j++) {
        sa = fmaf(g[j], a_src2[j], sa);
        da = fmaf(g[j], a_dst2[j], da);
    }
    if (c < 7) g2[(size_t)d * 8 + c] = g[c];
    if (c == 7) g2[(size_t)d * 8 + 7] = sa;
    if (c == 8) ad2[d] = da;
}

// ============ agg2 + log_softmax ============
__global__ __launch_bounds__(256) void agg2_kernel(
    const int* __restrict__ csr_off, const int* __restrict__ col,
    const float* __restrict__ ad2, const float* __restrict__ g2,
    const float* __restrict__ b2, float* __restrict__ out, int n) {
    int d = blockIdx.x * 4 + (threadIdx.x >> 6);
    if (d >= n) return;
    int lane = threadIdx.x & 63;
    int j = lane >> 3, cc = lane & 7;
    int bl = lane | 7;
    float adv = ad2[d];
    float vd = g2[(size_t)d * 8 + cc];
    float as2d = __shfl(vd, bl);
    float pd = (j == 0) ? __expf(lrelu(as2d + adv)) : 0.f;
    float denom = pd;
    float acc = pd * vd;
    int st = csr_off[d], en = csr_off[d + 1];
    for (int base = st; base < en; base += 8) {
        int eidx = base + j;
        bool valid = eidx < en;
        int s = valid ? col[eidx] : d;
        float val = g2[(size_t)s * 8 + cc];
        float as2s = __shfl(val, bl);
        float p = valid ? __expf(lrelu(as2s + adv)) : 0.f;
        denom += p;
        acc = fmaf(p, val, acc);
    }
    #pragma unroll
    for (int off = 8; off < 64; off <<= 1) {
        acc += __shfl_xor(acc, off);
        denom += __shfl_xor(denom, off);
    }
    float o = acc / denom + ((cc < 7) ? b2[cc] : 0.f);
    float m = (cc < 7) ? o : -1e30f;
    #pragma unroll
    for (int off = 1; off < 8; off <<= 1) m = fmaxf(m, __shfl_xor(m, off));
    float se = (cc < 7) ? __expf(o - m) : 0.f;
    #pragma unroll
    for (int off = 1; off < 8; off <<= 1) se += __shfl_xor(se, off);
    float lse = m + __logf(se);
    if (j == 0 && cc < 7) out[(size_t)d * 7 + cc] = o - lse;
}

extern "C" void kernel_launch(void* const* d_in, const int* in_sizes, int n_in,
                              void* d_out, int out_size, void* d_ws, size_t ws_size,
                              hipStream_t stream) {
    const float* x      = (const float*)d_in[0];
    const int*   ei     = (const int*)d_in[1];
    const float* W1     = (const float*)d_in[2];
    const float* a_src1 = (const float*)d_in[3];
    const float* a_dst1 = (const float*)d_in[4];
    const float* b1     = (const float*)d_in[5];
    const float* W2     = (const float*)d_in[6];
    const float* a_src2 = (const float*)d_in[7];
    const float* a_dst2 = (const float*)d_in[8];
    const float* b2     = (const float*)d_in[9];

    int N = in_sizes[0] / 512;
    int E = in_sizes[1] / 2;
    const int* esrc = ei;
    const int* edst = ei + E;
    int NB = (N + 255) >> 8;   // 391 dst-buckets of 256 nodes

    char* ws = (char*)d_ws;
    size_t off = 0;
    auto alloc = [&](size_t bytes) -> void* {
        void* p = ws + off;
        off += (bytes + 255) & ~(size_t)255;
        return p;
    };
    ushort_t* h1b  = (ushort_t*)alloc((size_t)N * 64 * 2);   // 128 B/row, line-aligned
    float* as1     = (float*)alloc((size_t)N * 8 * 4);
    float* ad1     = (float*)alloc((size_t)N * 8 * 4);
    float* g2      = (float*)alloc((size_t)N * 8 * 4);
    float* ad2     = (float*)alloc((size_t)N * 4);
    int*   csr_off = (int*)alloc((size_t)(N + 1) * 4);
    int*   col     = (int*)alloc((size_t)E * 4);
    int2*  ebuf    = (int2*)alloc((size_t)E * 8);
    ushort_t* Whi  = (ushort_t*)alloc(512 * 64 * 2);
    ushort_t* Wlo  = (ushort_t*)alloc(512 * 64 * 2);
    int*   bcnt    = (int*)alloc((size_t)NB * 4);
    int*   boff    = (int*)alloc((size_t)(NB + 1) * 4);
    int*   bcur    = (int*)alloc((size_t)NB * 4);

    hipMemsetAsync(bcnt, 0, (size_t)NB * 4, stream);

    int ntiles = (N + 15) / 16;
    int GB = (ntiles + 15) / 16;   // gemm blocks: 16 waves x 1 tile each

    hist_prep_kernel<<<128 + HWG, 256, 0, stream>>>(edst, bcnt, E, NB, W1, Whi, Wlo);
    bscan_kernel<<<1, 512, 0, stream>>>(bcnt, boff, bcur, csr_off, NB, N, E);
    gemm_bscatter_kernel<<<SB + GB, 1024, 0, stream>>>(x, Whi, Wlo, h1b, N,
                                                       esrc, edst, bcur, ebuf, E, NB,
                                                       a_src1, a_dst1, as1, ad1);
    finalize_kernel<<<NB, 256, 0, stream>>>(boff, ebuf, csr_off, col, N, NB);
    agg1_kernel<<<(N + 7) / 8, 256, 0, stream>>>(csr_off, col, h1b, as1, ad1, b1,
                                                 W2, a_src2, a_dst2, g2, ad2, N);
    agg2_kernel<<<(N + 3) / 4, 256, 0, stream>>>(csr_off, col, ad2, g2, b2,
                                                 (float*)d_out, N);
}

// Round 7
// 470.457 us; speedup vs baseline: 1.7941x; 1.7941x over previous
//
#include <hip/hip_runtime.h>
#include <hip/hip_bf16.h>

#define NEG_SLOPE 0.2f
#define SB 256          // bucket-scatter workgroups (fused into gemm kernel)
#define HWG 384         // histogram workgroups

typedef __attribute__((ext_vector_type(8))) short bfrag;
typedef __attribute__((ext_vector_type(4))) float f32x4;
typedef unsigned short ushort_t;

__device__ __forceinline__ float lrelu(float x) {
    return x >= 0.0f ? x : NEG_SLOPE * x;
}
__device__ __forceinline__ unsigned short f2bf(float f) {  // round-to-nearest-even
    unsigned int u = __float_as_uint(f);
    u += 0x7fffu + ((u >> 16) & 1u);
    return (unsigned short)(u >> 16);
}
__device__ __forceinline__ float bf2f(unsigned short h) {
    return __uint_as_float(((unsigned int)h) << 16);
}
__device__ __forceinline__ float u2lo(unsigned int u) {
    return __uint_as_float(u << 16);
}
__device__ __forceinline__ float u2hi(unsigned int u) {
    return __uint_as_float(u & 0xffff0000u);
}

// ============ K1: bucket histogram + W1 split-bf16 prep (fused) ============
__global__ __launch_bounds__(256) void hist_prep_kernel(
    const int* __restrict__ edst, int* __restrict__ bcnt, int E, int NB,
    const float* __restrict__ W1, ushort_t* __restrict__ Whi,
    ushort_t* __restrict__ Wlo) {
    if (blockIdx.x < 128) {
        int t = blockIdx.x * 256 + threadIdx.x;  // 32768
        int k = t >> 6, c = t & 63;
        float w = W1[t];
        unsigned short hi = f2bf(w);
        float rem = w - bf2f(hi);
        int dst = (k >> 7) * 8192 + c * 128 + (k & 127);
        Whi[dst] = hi;
        Wlo[dst] = f2bf(rem);
        return;
    }
    __shared__ int hist[512];
    int tid = threadIdx.x;
    for (int i = tid; i < NB; i += 256) hist[i] = 0;
    __syncthreads();
    int wg = blockIdx.x - 128;
    int CH = (E + HWG - 1) / HWG;
    int st = wg * CH, en = min(st + CH, E);
    for (int i = st + tid; i < en; i += 256)
        atomicAdd(&hist[edst[i] >> 8], 1);
    __syncthreads();
    for (int i = tid; i < NB; i += 256)
        if (hist[i] > 0) atomicAdd(&bcnt[i], hist[i]);
}

// ============ K2: bucket exclusive scan (one WG) ============
__global__ __launch_bounds__(512) void bscan_kernel(
    const int* __restrict__ bcnt, int* __restrict__ boff, int* __restrict__ bcur,
    int* __restrict__ csr_off, int NB, int N, int E) {
    __shared__ int s[512];
    int t = threadIdx.x;
    int v = (t < NB) ? bcnt[t] : 0;
    s[t] = v;
    __syncthreads();
    for (int off = 1; off < 512; off <<= 1) {
        int tv = (t >= off) ? s[t - off] : 0;
        __syncthreads();
        s[t] += tv;
        __syncthreads();
    }
    if (t < NB) {
        int o = s[t] - v;
        boff[t] = o;
        bcur[t] = o;
    }
    if (t == 0) {
        boff[NB] = E;
        csr_off[N] = E;
    }
}

// ============ K3: fused GEMM1 + bucket scatter + attention coeffs ============
// blocks [0,SB): scatter edges into bucket-contiguous ebuf (int2 {src,dst}).
// blocks [SB,...): MFMA gemm. ALL of W (hi+lo, 128 KB) staged into LDS ONCE
// per block (XOR-swizzled, conflict-free), then 16 waves each own a 16-row
// tile — zero barriers in the K loop, W reused 16x per block.
// __launch_bounds__(1024, 4): 4 waves/EU -> full 128 VGPR budget (R6's
// unqualified bounds capped at 64 VGPR -> 750 MB scratch-spill traffic).
__global__ __launch_bounds__(1024, 4) void gemm_bscatter_kernel(
    const float* __restrict__ x, const ushort_t* __restrict__ Whi,
    const ushort_t* __restrict__ Wlo, ushort_t* __restrict__ h1b, int n,
    const int* __restrict__ esrc, const int* __restrict__ edst,
    int* __restrict__ bcur, int2* __restrict__ ebuf, int E, int NB,
    const float* __restrict__ a_src1, const float* __restrict__ a_dst1,
    float* __restrict__ as1, float* __restrict__ ad1) {
    __shared__ __align__(16) ushort_t Wh[32768];   // 64 KB: [p][row][k] swizzled
    __shared__ __align__(16) ushort_t Wl[32768];   // 64 KB
    const int tid = threadIdx.x;   // 0..1023

    if (blockIdx.x < SB) {
        // ---- bucket scatter (uses Wh as int scratch) ----
        int* hist = (int*)Wh;
        int* base = hist + 512;
        int* rank = hist + 1024;
        for (int i = tid; i < NB; i += 1024) { hist[i] = 0; rank[i] = 0; }
        __syncthreads();
        int CH = (E + SB - 1) / SB;
        int st = blockIdx.x * CH, en = min(st + CH, E);
        for (int i = st + tid; i < en; i += 1024)
            atomicAdd(&hist[edst[i] >> 8], 1);
        __syncthreads();
        for (int b = tid; b < NB; b += 1024)
            if (hist[b] > 0) base[b] = atomicAdd(&bcur[b], hist[b]);
        __syncthreads();
        for (int i = st + tid; i < en; i += 1024) {
            int d = edst[i], s = esrc[i];
            int b = d >> 8;
            int r = atomicAdd(&rank[b], 1);
            ebuf[base[b] + r] = make_int2(s, d);
        }
        return;
    }

    // ---- stage all of W into LDS, swizzled (once per block) ----
    // global Whi layout: idx = p*8192 + row*128 + k ; LDS ushort idx ^= (row&7)<<3
    #pragma unroll
    for (int i = 0; i < 4; i++) {
        int lin = (tid + i * 1024) * 8;
        int row = (lin >> 7) & 63;
        int swz = lin ^ ((row & 7) << 3);
        *(bfrag*)&Wh[swz] = *(const bfrag*)&Whi[lin];
        *(bfrag*)&Wl[swz] = *(const bfrag*)&Wlo[lin];
    }
    __syncthreads();

    const int lane = tid & 63;
    const int wave = tid >> 6;      // 0..15
    const int l15 = lane & 15;
    const int lq = lane >> 4;
    const int r7s = (l15 & 7) << 3; // read-side swizzle (ushort units)

    const int ntiles = (n + 15) >> 4;
    const int tstride = (gridDim.x - SB) * 16;

    for (int tile = (blockIdx.x - SB) * 16 + wave; tile < ntiles; tile += tstride) {
        const int wb = tile * 16;
        f32x4 acc[4];
        #pragma unroll
        for (int t = 0; t < 4; t++) acc[t] = (f32x4){0.f, 0.f, 0.f, 0.f};

        const int arow = min(wb + l15, n - 1);
        const float* xr = x + (size_t)arow * 512;

        #pragma unroll 1
        for (int p = 0; p < 4; p++) {
            #pragma unroll
            for (int step = 0; step < 4; step++) {
                int kloc = step * 32 + lq * 8;
                int kb = p * 128 + kloc;
                float4 v0 = *(const float4*)&xr[kb];
                float4 v1 = *(const float4*)&xr[kb + 4];
                float xf[8] = {v0.x, v0.y, v0.z, v0.w, v1.x, v1.y, v1.z, v1.w};
                bfrag ah, al;
                #pragma unroll
                for (int j = 0; j < 8; j++) {
                    unsigned short hi = f2bf(xf[j]);
                    float rem = xf[j] - bf2f(hi);
                    ah[j] = (short)hi;
                    al[j] = (short)f2bf(rem);
                }
                #pragma unroll
                for (int t = 0; t < 4; t++) {
                    int nrow = t * 16 + l15;
                    int bidx = ((p * 64 + nrow) * 128 + kloc) ^ r7s;
                    bfrag bh = *(const bfrag*)&Wh[bidx];
                    bfrag bl = *(const bfrag*)&Wl[bidx];
                    acc[t] = __builtin_amdgcn_mfma_f32_16x16x32_bf16(al, bh, acc[t], 0, 0, 0);
                    acc[t] = __builtin_amdgcn_mfma_f32_16x16x32_bf16(ah, bl, acc[t], 0, 0, 0);
                    acc[t] = __builtin_amdgcn_mfma_f32_16x16x32_bf16(ah, bh, acc[t], 0, 0, 0);
                }
            }
        }
        // ---- h1b write (bf16 rows, 128 B line-aligned) ----
        #pragma unroll
        for (int t = 0; t < 4; t++) {
            #pragma unroll
            for (int reg = 0; reg < 4; reg++) {
                int grow = wb + lq * 4 + reg;
                if (grow < n) h1b[(size_t)grow * 64 + t * 16 + l15] = f2bf(acc[t][reg]);
            }
        }
        // ---- attention coefficients from fp32 accumulators ----
        const int j7 = l15 & 7;
        const int wrow = wb + lq * 4 + (j7 & 3);
        #pragma unroll
        for (int t = 0; t < 4; t++) {
            int cidx = t * 16 + l15;
            float cs = a_src1[cidx];
            float cd = a_dst1[cidx];
            float ps0 = acc[t][0] * cs, ps1 = acc[t][1] * cs;
            float ps2 = acc[t][2] * cs, ps3 = acc[t][3] * cs;
            float pd0 = acc[t][0] * cd, pd1 = acc[t][1] * cd;
            float pd2 = acc[t][2] * cd, pd3 = acc[t][3] * cd;
            #pragma unroll
            for (int off = 1; off < 8; off <<= 1) {
                ps0 += __shfl_xor(ps0, off);
                ps1 += __shfl_xor(ps1, off);
                ps2 += __shfl_xor(ps2, off);
                ps3 += __shfl_xor(ps3, off);
                pd0 += __shfl_xor(pd0, off);
                pd1 += __shfl_xor(pd1, off);
                pd2 += __shfl_xor(pd2, off);
                pd3 += __shfl_xor(pd3, off);
            }
            int h = (t << 1) | (l15 >> 3);
            if (wrow < n) {
                if (j7 < 4) {
                    float sv = j7 == 0 ? ps0 : j7 == 1 ? ps1 : j7 == 2 ? ps2 : ps3;
                    as1[wrow * 8 + h] = sv;
                } else {
                    float dv = j7 == 4 ? pd0 : j7 == 5 ? pd1 : j7 == 6 ? pd2 : pd3;
                    ad1[wrow * 8 + h] = dv;
                }
            }
        }
    }
}

// ============ K4: per-bucket CSR finalize ============
__global__ __launch_bounds__(256) void finalize_kernel(
    const int* __restrict__ boff, const int2* __restrict__ ebuf,
    int* __restrict__ csr_off, int* __restrict__ col, int N, int NB) {
    int tid = threadIdx.x;
    int b = blockIdx.x;
    __shared__ int cnt[256];
    __shared__ int cur[256];
    __shared__ int sc[256];
    cnt[tid] = 0;
    __syncthreads();
    int st = boff[b], en = boff[b + 1];
    for (int i = st + tid; i < en; i += 256)
        atomicAdd(&cnt[ebuf[i].y & 255], 1);
    __syncthreads();
    int v = cnt[tid];
    sc[tid] = v;
    __syncthreads();
    for (int off = 1; off < 256; off <<= 1) {
        int tv = (tid >= off) ? sc[tid - off] : 0;
        __syncthreads();
        sc[tid] += tv;
        __syncthreads();
    }
    int dbase = b << 8;
    int nd = min(256, N - dbase);
    int o = st + sc[tid] - v;   // exclusive
    if (tid < nd) {
        csr_off[dbase + tid] = o;
        cur[tid] = o;
    }
    __syncthreads();
    for (int i = st + tid; i < en; i += 256) {
        int2 p = ebuf[i];
        int r = atomicAdd(&cur[p.y & 255], 1);
        col[r] = p.x;
    }
}

// ============ agg1 + fused lin2 ============
__global__ __launch_bounds__(256) void agg1_kernel(
    const int* __restrict__ csr_off, const int* __restrict__ col,
    const ushort_t* __restrict__ h1b, const float* __restrict__ as1,
    const float* __restrict__ ad1,
    const float* __restrict__ b1, const float* __restrict__ W2,
    const float* __restrict__ a_src2, const float* __restrict__ a_dst2,
    float* __restrict__ g2, float* __restrict__ ad2, int n) {
    int d = blockIdx.x * 8 + (threadIdx.x >> 5);
    if (d >= n) return;
    int c = threadIdx.x & 31;
    int hd = c >> 2;
    const ushort_t* myrow = h1b + (size_t)d * 64;
    float adh = ad1[d * 8 + hd];
    float asd = as1[d * 8 + hd];
    float p0 = __expf(lrelu(asd + adh));
    unsigned int u = *(const unsigned int*)(myrow + c * 2);
    float denom = p0;
    float acc0 = p0 * u2lo(u);
    float acc1 = p0 * u2hi(u);
    int st = csr_off[d], en = csr_off[d + 1];
    int e = st;
    for (; e + 4 <= en; e += 4) {
        int s0 = col[e], s1 = col[e + 1], s2 = col[e + 2], s3 = col[e + 3];
        const ushort_t* r0 = h1b + (size_t)s0 * 64;
        const ushort_t* r1 = h1b + (size_t)s1 * 64;
        const ushort_t* r2 = h1b + (size_t)s2 * 64;
        const ushort_t* r3 = h1b + (size_t)s3 * 64;
        float a0 = as1[s0 * 8 + hd];
        float a1 = as1[s1 * 8 + hd];
        float a2 = as1[s2 * 8 + hd];
        float a3 = as1[s3 * 8 + hd];
        unsigned int u0 = *(const unsigned int*)(r0 + c * 2);
        unsigned int u1 = *(const unsigned int*)(r1 + c * 2);
        unsigned int u2 = *(const unsigned int*)(r2 + c * 2);
        unsigned int u3 = *(const unsigned int*)(r3 + c * 2);
        float q0 = __expf(lrelu(a0 + adh));
        float q1 = __expf(lrelu(a1 + adh));
        float q2 = __expf(lrelu(a2 + adh));
        float q3 = __expf(lrelu(a3 + adh));
        denom += (q0 + q1) + (q2 + q3);
        acc0 = fmaf(q0, u2lo(u0), acc0);
        acc1 = fmaf(q0, u2hi(u0), acc1);
        acc0 = fmaf(q1, u2lo(u1), acc0);
        acc1 = fmaf(q1, u2hi(u1), acc1);
        acc0 = fmaf(q2, u2lo(u2), acc0);
        acc1 = fmaf(q2, u2hi(u2), acc1);
        acc0 = fmaf(q3, u2lo(u3), acc0);
        acc1 = fmaf(q3, u2hi(u3), acc1);
    }
    for (; e < en; ++e) {
        int s0 = col[e];
        const ushort_t* r0 = h1b + (size_t)s0 * 64;
        float a0 = as1[s0 * 8 + hd];
        unsigned int u0 = *(const unsigned int*)(r0 + c * 2);
        float q0 = __expf(lrelu(a0 + adh));
        denom += q0;
        acc0 = fmaf(q0, u2lo(u0), acc0);
        acc1 = fmaf(q0, u2hi(u0), acc1);
    }
    float v0 = acc0 / denom + b1[2 * c];
    float v1 = acc1 / denom + b1[2 * c + 1];
    float h0 = v0 > 0.f ? v0 : (__expf(v0) - 1.f);
    float h1v = v1 > 0.f ? v1 : (__expf(v1) - 1.f);
    float g[7];
    #pragma unroll
    for (int j = 0; j < 7; j++) {
        float t = fmaf(h0, W2[(2 * c) * 7 + j], h1v * W2[(2 * c + 1) * 7 + j]);
        #pragma unroll
        for (int off = 1; off < 32; off <<= 1) t += __shfl_xor(t, off);
        g[j] = t;
    }
    float sa = 0.f, da = 0.f;
    #pragma unroll
    for (int j = 0; j < 7; j++) {
        sa = fmaf(g[j], a_src2[j], sa);
        da = fmaf(g[j], a_dst2[j], da);
    }
    if (c < 7) g2[(size_t)d * 8 + c] = g[c];
    if (c == 7) g2[(size_t)d * 8 + 7] = sa;
    if (c == 8) ad2[d] = da;
}

// ============ agg2 + log_softmax ============
__global__ __launch_bounds__(256) void agg2_kernel(
    const int* __restrict__ csr_off, const int* __restrict__ col,
    const float* __restrict__ ad2, const float* __restrict__ g2,
    const float* __restrict__ b2, float* __restrict__ out, int n) {
    int d = blockIdx.x * 4 + (threadIdx.x >> 6);
    if (d >= n) return;
    int lane = threadIdx.x & 63;
    int j = lane >> 3, cc = lane & 7;
    int bl = lane | 7;
    float adv = ad2[d];
    float vd = g2[(size_t)d * 8 + cc];
    float as2d = __shfl(vd, bl);
    float pd = (j == 0) ? __expf(lrelu(as2d + adv)) : 0.f;
    float denom = pd;
    float acc = pd * vd;
    int st = csr_off[d], en = csr_off[d + 1];
    for (int base = st; base < en; base += 8) {
        int eidx = base + j;
        bool valid = eidx < en;
        int s = valid ? col[eidx] : d;
        float val = g2[(size_t)s * 8 + cc];
        float as2s = __shfl(val, bl);
        float p = valid ? __expf(lrelu(as2s + adv)) : 0.f;
        denom += p;
        acc = fmaf(p, val, acc);
    }
    #pragma unroll
    for (int off = 8; off < 64; off <<= 1) {
        acc += __shfl_xor(acc, off);
        denom += __shfl_xor(denom, off);
    }
    float o = acc / denom + ((cc < 7) ? b2[cc] : 0.f);
    float m = (cc < 7) ? o : -1e30f;
    #pragma unroll
    for (int off = 1; off < 8; off <<= 1) m = fmaxf(m, __shfl_xor(m, off));
    float se = (cc < 7) ? __expf(o - m) : 0.f;
    #pragma unroll
    for (int off = 1; off < 8; off <<= 1) se += __shfl_xor(se, off);
    float lse = m + __logf(se);
    if (j == 0 && cc < 7) out[(size_t)d * 7 + cc] = o - lse;
}

extern "C" void kernel_launch(void* const* d_in, const int* in_sizes, int n_in,
                              void* d_out, int out_size, void* d_ws, size_t ws_size,
                              hipStream_t stream) {
    const float* x      = (const float*)d_in[0];
    const int*   ei     = (const int*)d_in[1];
    const float* W1     = (const float*)d_in[2];
    const float* a_src1 = (const float*)d_in[3];
    const float* a_dst1 = (const float*)d_in[4];
    const float* b1     = (const float*)d_in[5];
    const float* W2     = (const float*)d_in[6];
    const float* a_src2 = (const float*)d_in[7];
    const float* a_dst2 = (const float*)d_in[8];
    const float* b2     = (const float*)d_in[9];

    int N = in_sizes[0] / 512;
    int E = in_sizes[1] / 2;
    const int* esrc = ei;
    const int* edst = ei + E;
    int NB = (N + 255) >> 8;   // 391 dst-buckets of 256 nodes

    char* ws = (char*)d_ws;
    size_t off = 0;
    auto alloc = [&](size_t bytes) -> void* {
        void* p = ws + off;
        off += (bytes + 255) & ~(size_t)255;
        return p;
    };
    ushort_t* h1b  = (ushort_t*)alloc((size_t)N * 64 * 2);   // 128 B/row, line-aligned
    float* as1     = (float*)alloc((size_t)N * 8 * 4);
    float* ad1     = (float*)alloc((size_t)N * 8 * 4);
    float* g2      = (float*)alloc((size_t)N * 8 * 4);
    float* ad2     = (float*)alloc((size_t)N * 4);
    int*   csr_off = (int*)alloc((size_t)(N + 1) * 4);
    int*   col     = (int*)alloc((size_t)E * 4);
    int2*  ebuf    = (int2*)alloc((size_t)E * 8);
    ushort_t* Whi  = (ushort_t*)alloc(512 * 64 * 2);
    ushort_t* Wlo  = (ushort_t*)alloc(512 * 64 * 2);
    int*   bcnt    = (int*)alloc((size_t)NB * 4);
    int*   boff    = (int*)alloc((size_t)(NB + 1) * 4);
    int*   bcur    = (int*)alloc((size_t)NB * 4);

    hipMemsetAsync(bcnt, 0, (size_t)NB * 4, stream);

    int ntiles = (N + 15) / 16;
    int GB = (ntiles + 15) / 16;   // gemm blocks: 16 waves x 1 tile each

    hist_prep_kernel<<<128 + HWG, 256, 0, stream>>>(edst, bcnt, E, NB, W1, Whi, Wlo);
    bscan_kernel<<<1, 512, 0, stream>>>(bcnt, boff, bcur, csr_off, NB, N, E);
    gemm_bscatter_kernel<<<SB + GB, 1024, 0, stream>>>(x, Whi, Wlo, h1b, N,
                                                       esrc, edst, bcur, ebuf, E, NB,
                                                       a_src1, a_dst1, as1, ad1);
    finalize_kernel<<<NB, 256, 0, stream>>>(boff, ebuf, csr_off, col, N, NB);
    agg1_kernel<<<(N + 7) / 8, 256, 0, stream>>>(csr_off, col, h1b, as1, ad1, b1,
                                                 W2, a_src2, a_dst2, g2, ad2, N);
    agg2_kernel<<<(N + 3) / 4, 256, 0, stream>>>(csr_off, col, ad2, g2, b2,
                                                 (float*)d_out, N);
}

// Round 8
// 467.406 us; speedup vs baseline: 1.8059x; 1.0065x over previous
//
#include <hip/hip_runtime.h>
#include <hip/hip_bf16.h>

#define NEG_SLOPE 0.2f
#define GB 256          // uniform blocks: scatter chunk + W stage + gemm tiles
#define HWG 384         // histogram workgroups

typedef __attribute__((ext_vector_type(8))) short bfrag;
typedef __attribute__((ext_vector_type(4))) float f32x4;
typedef unsigned short ushort_t;

__device__ __forceinline__ float lrelu(float x) {
    return x >= 0.0f ? x : NEG_SLOPE * x;
}
__device__ __forceinline__ unsigned short f2bf(float f) {  // round-to-nearest-even
    unsigned int u = __float_as_uint(f);
    u += 0x7fffu + ((u >> 16) & 1u);
    return (unsigned short)(u >> 16);
}
__device__ __forceinline__ float bf2f(unsigned short h) {
    return __uint_as_float(((unsigned int)h) << 16);
}
__device__ __forceinline__ float u2lo(unsigned int u) {
    return __uint_as_float(u << 16);
}
__device__ __forceinline__ float u2hi(unsigned int u) {
    return __uint_as_float(u & 0xffff0000u);
}

// ============ K1: bucket histogram + W1 split-bf16 prep (fused) ============
__global__ __launch_bounds__(256) void hist_prep_kernel(
    const int* __restrict__ edst, int* __restrict__ bcnt, int E, int NB,
    const float* __restrict__ W1, ushort_t* __restrict__ Whi,
    ushort_t* __restrict__ Wlo) {
    if (blockIdx.x < 128) {
        int t = blockIdx.x * 256 + threadIdx.x;  // 32768
        int k = t >> 6, c = t & 63;
        float w = W1[t];
        unsigned short hi = f2bf(w);
        float rem = w - bf2f(hi);
        int dst = (k >> 7) * 8192 + c * 128 + (k & 127);
        Whi[dst] = hi;
        Wlo[dst] = f2bf(rem);
        return;
    }
    __shared__ int hist[512];
    int tid = threadIdx.x;
    for (int i = tid; i < NB; i += 256) hist[i] = 0;
    __syncthreads();
    int wg = blockIdx.x - 128;
    int CH = (E + HWG - 1) / HWG;
    int st = wg * CH, en = min(st + CH, E);
    for (int i = st + tid; i < en; i += 256)
        atomicAdd(&hist[edst[i] >> 8], 1);
    __syncthreads();
    for (int i = tid; i < NB; i += 256)
        if (hist[i] > 0) atomicAdd(&bcnt[i], hist[i]);
}

// ============ K2: bucket exclusive scan (one WG) ============
__global__ __launch_bounds__(512) void bscan_kernel(
    const int* __restrict__ bcnt, int* __restrict__ boff, int* __restrict__ bcur,
    int* __restrict__ csr_off, int NB, int N, int E) {
    __shared__ int s[512];
    int t = threadIdx.x;
    int v = (t < NB) ? bcnt[t] : 0;
    s[t] = v;
    __syncthreads();
    for (int off = 1; off < 512; off <<= 1) {
        int tv = (t >= off) ? s[t - off] : 0;
        __syncthreads();
        s[t] += tv;
        __syncthreads();
    }
    if (t < NB) {
        int o = s[t] - v;
        boff[t] = o;
        bcur[t] = o;
    }
    if (t == 0) {
        boff[NB] = E;
        csr_off[N] = E;
    }
}

// ============ K3: fused scatter + GEMM1 + attention coeffs ============
// UNIFORM grid of 256 blocks (1/CU, single round):
//   phase 1: scatter this block's E/256 edge chunk into bucket regions
//   phase 2: stage ALL of W (hi+lo, 128 KB) into LDS, XOR-swizzled
//   phase 3: grid-stride wave-tile loop (16 rows/tile), zero barriers
// __launch_bounds__(1024, 4): 4 waves/EU -> full VGPR budget (R6 lesson:
// default bounds capped 64 VGPR -> 750 MB scratch spill).
__global__ __launch_bounds__(1024, 4) void gemm_bscatter_kernel(
    const float* __restrict__ x, const ushort_t* __restrict__ Whi,
    const ushort_t* __restrict__ Wlo, ushort_t* __restrict__ h1b, int n,
    const int* __restrict__ esrc, const int* __restrict__ edst,
    int* __restrict__ bcur, int2* __restrict__ ebuf, int E, int NB,
    const float* __restrict__ a_src1, const float* __restrict__ a_dst1,
    float* __restrict__ as1, float* __restrict__ ad1) {
    __shared__ __align__(16) ushort_t Wh[32768];   // 64 KB: [p][row][k] swizzled
    __shared__ __align__(16) ushort_t Wl[32768];   // 64 KB
    const int tid = threadIdx.x;   // 0..1023

    // ---- phase 1: bucket scatter (uses Wh as int scratch) ----
    {
        int* hist = (int*)Wh;
        int* base = hist + 512;
        int* rank = hist + 1024;
        for (int i = tid; i < NB; i += 1024) { hist[i] = 0; rank[i] = 0; }
        __syncthreads();
        int CH = (E + GB - 1) / GB;
        int st = blockIdx.x * CH, en = min(st + CH, E);
        for (int i = st + tid; i < en; i += 1024)
            atomicAdd(&hist[edst[i] >> 8], 1);
        __syncthreads();
        for (int b = tid; b < NB; b += 1024)
            if (hist[b] > 0) base[b] = atomicAdd(&bcur[b], hist[b]);
        __syncthreads();
        for (int i = st + tid; i < en; i += 1024) {
            int d = edst[i], s = esrc[i];
            int b = d >> 8;
            int r = atomicAdd(&rank[b], 1);
            ebuf[base[b] + r] = make_int2(s, d);
        }
        __syncthreads();   // LDS about to be overwritten by W staging
    }

    // ---- phase 2: stage all of W into LDS, swizzled ----
    // global Whi layout: idx = p*8192 + row*128 + k ; LDS ushort idx ^= (row&7)<<3
    #pragma unroll
    for (int i = 0; i < 4; i++) {
        int lin = (tid + i * 1024) * 8;
        int row = (lin >> 7) & 63;
        int swz = lin ^ ((row & 7) << 3);
        *(bfrag*)&Wh[swz] = *(const bfrag*)&Whi[lin];
        *(bfrag*)&Wl[swz] = *(const bfrag*)&Wlo[lin];
    }
    __syncthreads();

    // ---- phase 3: gemm tiles (no barriers) ----
    const int lane = tid & 63;
    const int wave = tid >> 6;      // 0..15
    const int l15 = lane & 15;
    const int lq = lane >> 4;
    const int r7s = (l15 & 7) << 3; // read-side swizzle (ushort units)

    const int ntiles = (n + 15) >> 4;
    const int tstride = GB * 16;

    for (int tile = blockIdx.x * 16 + wave; tile < ntiles; tile += tstride) {
        const int wb = tile * 16;
        f32x4 acc[4];
        #pragma unroll
        for (int t = 0; t < 4; t++) acc[t] = (f32x4){0.f, 0.f, 0.f, 0.f};

        const int arow = min(wb + l15, n - 1);
        const float* xr = x + (size_t)arow * 512;

        #pragma unroll 1
        for (int p = 0; p < 4; p++) {
            #pragma unroll
            for (int step = 0; step < 4; step++) {
                int kloc = step * 32 + lq * 8;
                int kb = p * 128 + kloc;
                float4 v0 = *(const float4*)&xr[kb];
                float4 v1 = *(const float4*)&xr[kb + 4];
                float xf[8] = {v0.x, v0.y, v0.z, v0.w, v1.x, v1.y, v1.z, v1.w};
                bfrag ah, al;
                #pragma unroll
                for (int j = 0; j < 8; j++) {
                    unsigned short hi = f2bf(xf[j]);
                    float rem = xf[j] - bf2f(hi);
                    ah[j] = (short)hi;
                    al[j] = (short)f2bf(rem);
                }
                #pragma unroll
                for (int t = 0; t < 4; t++) {
                    int nrow = t * 16 + l15;
                    int bidx = ((p * 64 + nrow) * 128 + kloc) ^ r7s;
                    bfrag bh = *(const bfrag*)&Wh[bidx];
                    bfrag bl = *(const bfrag*)&Wl[bidx];
                    acc[t] = __builtin_amdgcn_mfma_f32_16x16x32_bf16(al, bh, acc[t], 0, 0, 0);
                    acc[t] = __builtin_amdgcn_mfma_f32_16x16x32_bf16(ah, bl, acc[t], 0, 0, 0);
                    acc[t] = __builtin_amdgcn_mfma_f32_16x16x32_bf16(ah, bh, acc[t], 0, 0, 0);
                }
            }
        }
        // ---- h1b write (bf16 rows, 128 B line-aligned) ----
        #pragma unroll
        for (int t = 0; t < 4; t++) {
            #pragma unroll
            for (int reg = 0; reg < 4; reg++) {
                int grow = wb + lq * 4 + reg;
                if (grow < n) h1b[(size_t)grow * 64 + t * 16 + l15] = f2bf(acc[t][reg]);
            }
        }
        // ---- attention coefficients from fp32 accumulators ----
        const int j7 = l15 & 7;
        const int wrow = wb + lq * 4 + (j7 & 3);
        #pragma unroll
        for (int t = 0; t < 4; t++) {
            int cidx = t * 16 + l15;
            float cs = a_src1[cidx];
            float cd = a_dst1[cidx];
            float ps0 = acc[t][0] * cs, ps1 = acc[t][1] * cs;
            float ps2 = acc[t][2] * cs, ps3 = acc[t][3] * cs;
            float pd0 = acc[t][0] * cd, pd1 = acc[t][1] * cd;
            float pd2 = acc[t][2] * cd, pd3 = acc[t][3] * cd;
            #pragma unroll
            for (int off = 1; off < 8; off <<= 1) {
                ps0 += __shfl_xor(ps0, off);
                ps1 += __shfl_xor(ps1, off);
                ps2 += __shfl_xor(ps2, off);
                ps3 += __shfl_xor(ps3, off);
                pd0 += __shfl_xor(pd0, off);
                pd1 += __shfl_xor(pd1, off);
                pd2 += __shfl_xor(pd2, off);
                pd3 += __shfl_xor(pd3, off);
            }
            int h = (t << 1) | (l15 >> 3);
            if (wrow < n) {
                if (j7 < 4) {
                    float sv = j7 == 0 ? ps0 : j7 == 1 ? ps1 : j7 == 2 ? ps2 : ps3;
                    as1[wrow * 8 + h] = sv;
                } else {
                    float dv = j7 == 4 ? pd0 : j7 == 5 ? pd1 : j7 == 6 ? pd2 : pd3;
                    ad1[wrow * 8 + h] = dv;
                }
            }
        }
    }
}

// ============ K4: per-bucket CSR finalize ============
__global__ __launch_bounds__(256) void finalize_kernel(
    const int* __restrict__ boff, const int2* __restrict__ ebuf,
    int* __restrict__ csr_off, int* __restrict__ col, int N, int NB) {
    int tid = threadIdx.x;
    int b = blockIdx.x;
    __shared__ int cnt[256];
    __shared__ int cur[256];
    __shared__ int sc[256];
    cnt[tid] = 0;
    __syncthreads();
    int st = boff[b], en = boff[b + 1];
    for (int i = st + tid; i < en; i += 256)
        atomicAdd(&cnt[ebuf[i].y & 255], 1);
    __syncthreads();
    int v = cnt[tid];
    sc[tid] = v;
    __syncthreads();
    for (int off = 1; off < 256; off <<= 1) {
        int tv = (tid >= off) ? sc[tid - off] : 0;
        __syncthreads();
        sc[tid] += tv;
        __syncthreads();
    }
    int dbase = b << 8;
    int nd = min(256, N - dbase);
    int o = st + sc[tid] - v;   // exclusive
    if (tid < nd) {
        csr_off[dbase + tid] = o;
        cur[tid] = o;
    }
    __syncthreads();
    for (int i = st + tid; i < en; i += 256) {
        int2 p = ebuf[i];
        int r = atomicAdd(&cur[p.y & 255], 1);
        col[r] = p.x;
    }
}

// ============ agg1 + fused lin2 ============
__global__ __launch_bounds__(256) void agg1_kernel(
    const int* __restrict__ csr_off, const int* __restrict__ col,
    const ushort_t* __restrict__ h1b, const float* __restrict__ as1,
    const float* __restrict__ ad1,
    const float* __restrict__ b1, const float* __restrict__ W2,
    const float* __restrict__ a_src2, const float* __restrict__ a_dst2,
    float* __restrict__ g2, float* __restrict__ ad2, int n) {
    int d = blockIdx.x * 8 + (threadIdx.x >> 5);
    if (d >= n) return;
    int c = threadIdx.x & 31;
    int hd = c >> 2;
    const ushort_t* myrow = h1b + (size_t)d * 64;
    float adh = ad1[d * 8 + hd];
    float asd = as1[d * 8 + hd];
    float p0 = __expf(lrelu(asd + adh));
    unsigned int u = *(const unsigned int*)(myrow + c * 2);
    float denom = p0;
    float acc0 = p0 * u2lo(u);
    float acc1 = p0 * u2hi(u);
    int st = csr_off[d], en = csr_off[d + 1];
    int e = st;
    for (; e + 4 <= en; e += 4) {
        int s0 = col[e], s1 = col[e + 1], s2 = col[e + 2], s3 = col[e + 3];
        const ushort_t* r0 = h1b + (size_t)s0 * 64;
        const ushort_t* r1 = h1b + (size_t)s1 * 64;
        const ushort_t* r2 = h1b + (size_t)s2 * 64;
        const ushort_t* r3 = h1b + (size_t)s3 * 64;
        float a0 = as1[s0 * 8 + hd];
        float a1 = as1[s1 * 8 + hd];
        float a2 = as1[s2 * 8 + hd];
        float a3 = as1[s3 * 8 + hd];
        unsigned int u0 = *(const unsigned int*)(r0 + c * 2);
        unsigned int u1 = *(const unsigned int*)(r1 + c * 2);
        unsigned int u2 = *(const unsigned int*)(r2 + c * 2);
        unsigned int u3 = *(const unsigned int*)(r3 + c * 2);
        float q0 = __expf(lrelu(a0 + adh));
        float q1 = __expf(lrelu(a1 + adh));
        float q2 = __expf(lrelu(a2 + adh));
        float q3 = __expf(lrelu(a3 + adh));
        denom += (q0 + q1) + (q2 + q3);
        acc0 = fmaf(q0, u2lo(u0), acc0);
        acc1 = fmaf(q0, u2hi(u0), acc1);
        acc0 = fmaf(q1, u2lo(u1), acc0);
        acc1 = fmaf(q1, u2hi(u1), acc1);
        acc0 = fmaf(q2, u2lo(u2), acc0);
        acc1 = fmaf(q2, u2hi(u2), acc1);
        acc0 = fmaf(q3, u2lo(u3), acc0);
        acc1 = fmaf(q3, u2hi(u3), acc1);
    }
    for (; e < en; ++e) {
        int s0 = col[e];
        const ushort_t* r0 = h1b + (size_t)s0 * 64;
        float a0 = as1[s0 * 8 + hd];
        unsigned int u0 = *(const unsigned int*)(r0 + c * 2);
        float q0 = __expf(lrelu(a0 + adh));
        denom += q0;
        acc0 = fmaf(q0, u2lo(u0), acc0);
        acc1 = fmaf(q0, u2hi(u0), acc1);
    }
    float v0 = acc0 / denom + b1[2 * c];
    float v1 = acc1 / denom + b1[2 * c + 1];
    float h0 = v0 > 0.f ? v0 : (__expf(v0) - 1.f);
    float h1v = v1 > 0.f ? v1 : (__expf(v1) - 1.f);
    float g[7];
    #pragma unroll
    for (int j = 0; j < 7; j++) {
        float t = fmaf(h0, W2[(2 * c) * 7 + j], h1v * W2[(2 * c + 1) * 7 + j]);
        #pragma unroll
        for (int off = 1; off < 32; off <<= 1) t += __shfl_xor(t, off);
        g[j] = t;
    }
    float sa = 0.f, da = 0.f;
    #pragma unroll
    for (int j = 0; j < 7; j++) {
        sa = fmaf(g[j], a_src2[j], sa);
        da = fmaf(g[j], a_dst2[j], da);
    }
    if (c < 7) g2[(size_t)d * 8 + c] = g[c];
    if (c == 7) g2[(size_t)d * 8 + 7] = sa;
    if (c == 8) ad2[d] = da;
}

// ============ agg2 + log_softmax ============
__global__ __launch_bounds__(256) void agg2_kernel(
    const int* __restrict__ csr_off, const int* __restrict__ col,
    const float* __restrict__ ad2, const float* __restrict__ g2,
    const float* __restrict__ b2, float* __restrict__ out, int n) {
    int d = blockIdx.x * 4 + (threadIdx.x >> 6);
    if (d >= n) return;
    int lane = threadIdx.x & 63;
    int j = lane >> 3, cc = lane & 7;
    int bl = lane | 7;
    float adv = ad2[d];
    float vd = g2[(size_t)d * 8 + cc];
    float as2d = __shfl(vd, bl);
    float pd = (j == 0) ? __expf(lrelu(as2d + adv)) : 0.f;
    float denom = pd;
    float acc = pd * vd;
    int st = csr_off[d], en = csr_off[d + 1];
    for (int base = st; base < en; base += 8) {
        int eidx = base + j;
        bool valid = eidx < en;
        int s = valid ? col[eidx] : d;
        float val = g2[(size_t)s * 8 + cc];
        float as2s = __shfl(val, bl);
        float p = valid ? __expf(lrelu(as2s + adv)) : 0.f;
        denom += p;
        acc = fmaf(p, val, acc);
    }
    #pragma unroll
    for (int off = 8; off < 64; off <<= 1) {
        acc += __shfl_xor(acc, off);
        denom += __shfl_xor(denom, off);
    }
    float o = acc / denom + ((cc < 7) ? b2[cc] : 0.f);
    float m = (cc < 7) ? o : -1e30f;
    #pragma unroll
    for (int off = 1; off < 8; off <<= 1) m = fmaxf(m, __shfl_xor(m, off));
    float se = (cc < 7) ? __expf(o - m) : 0.f;
    #pragma unroll
    for (int off = 1; off < 8; off <<= 1) se += __shfl_xor(se, off);
    float lse = m + __logf(se);
    if (j == 0 && cc < 7) out[(size_t)d * 7 + cc] = o - lse;
}

extern "C" void kernel_launch(void* const* d_in, const int* in_sizes, int n_in,
                              void* d_out, int out_size, void* d_ws, size_t ws_size,
                              hipStream_t stream) {
    const float* x      = (const float*)d_in[0];
    const int*   ei     = (const int*)d_in[1];
    const float* W1     = (const float*)d_in[2];
    const float* a_src1 = (const float*)d_in[3];
    const float* a_dst1 = (const float*)d_in[4];
    const float* b1     = (const float*)d_in[5];
    const float* W2     = (const float*)d_in[6];
    const float* a_src2 = (const float*)d_in[7];
    const float* a_dst2 = (const float*)d_in[8];
    const float* b2     = (const float*)d_in[9];

    int N = in_sizes[0] / 512;
    int E = in_sizes[1] / 2;
    const int* esrc = ei;
    const int* edst = ei + E;
    int NB = (N + 255) >> 8;   // 391 dst-buckets of 256 nodes

    char* ws = (char*)d_ws;
    size_t off = 0;
    auto alloc = [&](size_t bytes) -> void* {
        void* p = ws + off;
        off += (bytes + 255) & ~(size_t)255;
        return p;
    };
    ushort_t* h1b  = (ushort_t*)alloc((size_t)N * 64 * 2);   // 128 B/row, line-aligned
    float* as1     = (float*)alloc((size_t)N * 8 * 4);
    float* ad1     = (float*)alloc((size_t)N * 8 * 4);
    float* g2      = (float*)alloc((size_t)N * 8 * 4);
    float* ad2     = (float*)alloc((size_t)N * 4);
    int*   csr_off = (int*)alloc((size_t)(N + 1) * 4);
    int*   col     = (int*)alloc((size_t)E * 4);
    int2*  ebuf    = (int2*)alloc((size_t)E * 8);
    ushort_t* Whi  = (ushort_t*)alloc(512 * 64 * 2);
    ushort_t* Wlo  = (ushort_t*)alloc(512 * 64 * 2);
    int*   bcnt    = (int*)alloc((size_t)NB * 4);
    int*   boff    = (int*)alloc((size_t)(NB + 1) * 4);
    int*   bcur    = (int*)alloc((size_t)NB * 4);

    hipMemsetAsync(bcnt, 0, (size_t)NB * 4, stream);

    hist_prep_kernel<<<128 + HWG, 256, 0, stream>>>(edst, bcnt, E, NB, W1, Whi, Wlo);
    bscan_kernel<<<1, 512, 0, stream>>>(bcnt, boff, bcur, csr_off, NB, N, E);
    gemm_bscatter_kernel<<<GB, 1024, 0, stream>>>(x, Whi, Wlo, h1b, N,
                                                  esrc, edst, bcur, ebuf, E, NB,
                                                  a_src1, a_dst1, as1, ad1);
    finalize_kernel<<<NB, 256, 0, stream>>>(boff, ebuf, csr_off, col, N, NB);
    agg1_kernel<<<(N + 7) / 8, 256, 0, stream>>>(csr_off, col, h1b, as1, ad1, b1,
                                                 W2, a_src2, a_dst2, g2, ad2, N);
    agg2_kernel<<<(N + 3) / 4, 256, 0, stream>>>(csr_off, col, ad2, g2, b2,
                                                 (float*)d_out, N);
}

// Round 9
// 463.676 us; speedup vs baseline: 1.8204x; 1.0080x over previous
//
#include <hip/hip_runtime.h>
#include <hip/hip_bf16.h>

#define NEG_SLOPE 0.2f
#define SBK 256         // scatter chunks (= hist chunks = scatter blocks)

typedef __attribute__((ext_vector_type(8))) short bfrag;
typedef __attribute__((ext_vector_type(4))) float f32x4;
typedef unsigned short ushort_t;

__device__ __forceinline__ float lrelu(float x) {
    return x >= 0.0f ? x : NEG_SLOPE * x;
}
__device__ __forceinline__ unsigned short f2bf(float f) {  // round-to-nearest-even
    unsigned int u = __float_as_uint(f);
    u += 0x7fffu + ((u >> 16) & 1u);
    return (unsigned short)(u >> 16);
}
__device__ __forceinline__ float bf2f(unsigned short h) {
    return __uint_as_float(((unsigned int)h) << 16);
}
__device__ __forceinline__ float u2lo(unsigned int u) {
    return __uint_as_float(u << 16);
}
__device__ __forceinline__ float u2hi(unsigned int u) {
    return __uint_as_float(u & 0xffff0000u);
}

// ============ K1: per-chunk bucket histograms + W1 split-bf16 prep ============
// blocks [0,128): prep W1 -> transposed hi/lo bf16.
// blocks [128,128+SBK): chunk s histogram -> cnt2d[b][s]  (NO global atomics)
__global__ __launch_bounds__(256) void hist_prep_kernel(
    const int* __restrict__ edst, int* __restrict__ cnt2d, int E, int NB,
    const float* __restrict__ W1, ushort_t* __restrict__ Whi,
    ushort_t* __restrict__ Wlo) {
    if (blockIdx.x < 128) {
        int t = blockIdx.x * 256 + threadIdx.x;  // 32768
        int k = t >> 6, c = t & 63;
        float w = W1[t];
        unsigned short hi = f2bf(w);
        float rem = w - bf2f(hi);
        int dst = (k >> 7) * 8192 + c * 128 + (k & 127);
        Whi[dst] = hi;
        Wlo[dst] = f2bf(rem);
        return;
    }
    __shared__ int hist[512];
    int tid = threadIdx.x;
    for (int i = tid; i < 512; i += 256) hist[i] = 0;
    __syncthreads();
    int s = blockIdx.x - 128;           // chunk id 0..SBK-1
    int CH = (E + SBK - 1) / SBK;
    int st = s * CH, en = min(st + CH, E);
    for (int i = st + tid; i < en; i += 256)
        atomicAdd(&hist[edst[i] >> 8], 1);
    __syncthreads();
    for (int b = tid; b < NB; b += 256)
        cnt2d[b * SBK + s] = hist[b];
}

// ============ K2a: per-bucket exclusive scan over chunks ============
// block b: scan cnt2d[b][0..SBK) in place (exclusive); total -> bcnt[b]
__global__ __launch_bounds__(256) void scan_cols_kernel(
    int* __restrict__ cnt2d, int* __restrict__ bcnt, int NB) {
    int b = blockIdx.x;
    int t = threadIdx.x;
    __shared__ int sc[256];
    int v = cnt2d[b * SBK + t];
    sc[t] = v;
    __syncthreads();
    for (int off = 1; off < 256; off <<= 1) {
        int tv = (t >= off) ? sc[t - off] : 0;
        __syncthreads();
        sc[t] += tv;
        __syncthreads();
    }
    cnt2d[b * SBK + t] = sc[t] - v;   // exclusive prefix within bucket
    if (t == 255) bcnt[b] = sc[255];
}

// ============ K2b: bucket exclusive scan (one WG) ============
__global__ __launch_bounds__(512) void bscan_kernel(
    const int* __restrict__ bcnt, int* __restrict__ boff,
    int* __restrict__ csr_off, int NB, int N, int E) {
    __shared__ int s[512];
    int t = threadIdx.x;
    int v = (t < NB) ? bcnt[t] : 0;
    s[t] = v;
    __syncthreads();
    for (int off = 1; off < 512; off <<= 1) {
        int tv = (t >= off) ? s[t - off] : 0;
        __syncthreads();
        s[t] += tv;
        __syncthreads();
    }
    if (t < NB) boff[t] = s[t] - v;
    if (t == 0) {
        boff[NB] = E;
        csr_off[N] = E;
    }
}

// ============ K3: bucket scatter — ZERO global atomics ============
// block s: base[b] = boff[b] + cnt2d[b][s] (deterministic); rank in LDS only.
// ebuf packed: (src << 8) | (dst & 255)   [src < 2^17, dloc 8 bits]
__global__ __launch_bounds__(1024) void scatter_kernel(
    const int* __restrict__ esrc, const int* __restrict__ edst,
    const int* __restrict__ boff, const int* __restrict__ cnt2d,
    int* __restrict__ ebuf, int E, int NB) {
    __shared__ int base[512];
    __shared__ int rank[512];
    int tid = threadIdx.x;
    int s = blockIdx.x;
    for (int b = tid; b < NB; b += 1024) {
        base[b] = boff[b] + cnt2d[b * SBK + s];
        rank[b] = 0;
    }
    __syncthreads();
    int CH = (E + SBK - 1) / SBK;
    int st = s * CH, en = min(st + CH, E);
    for (int i = st + tid; i < en; i += 1024) {
        int d = edst[i];
        int b = d >> 8;
        int r = atomicAdd(&rank[b], 1);
        ebuf[base[b] + r] = (esrc[i] << 8) | (d & 255);
    }
}

// ============ K4: GEMM1 + attention coeffs (standalone) ============
// 256 blocks (1/CU) x 1024 threads. Stage ALL of W (hi+lo, 128 KB) into LDS
// once (XOR-swizzled), then grid-stride 16-row wave-tiles, zero barriers.
// __launch_bounds__(1024, 4): full VGPR budget (R6 lesson: default bounds
// capped 64 VGPR -> 750 MB scratch spill).
__global__ __launch_bounds__(1024, 4) void gemm_kernel(
    const float* __restrict__ x, const ushort_t* __restrict__ Whi,
    const ushort_t* __restrict__ Wlo, ushort_t* __restrict__ h1b, int n,
    const float* __restrict__ a_src1, const float* __restrict__ a_dst1,
    float* __restrict__ as1, float* __restrict__ ad1) {
    __shared__ __align__(16) ushort_t Wh[32768];   // 64 KB swizzled
    __shared__ __align__(16) ushort_t Wl[32768];   // 64 KB
    const int tid = threadIdx.x;   // 0..1023

    // ---- stage all of W into LDS, swizzled ----
    // global layout: idx = p*8192 + row*128 + k ; LDS ushort idx ^= (row&7)<<3
    #pragma unroll
    for (int i = 0; i < 4; i++) {
        int lin = (tid + i * 1024) * 8;
        int row = (lin >> 7) & 63;
        int swz = lin ^ ((row & 7) << 3);
        *(bfrag*)&Wh[swz] = *(const bfrag*)&Whi[lin];
        *(bfrag*)&Wl[swz] = *(const bfrag*)&Wlo[lin];
    }
    __syncthreads();

    const int lane = tid & 63;
    const int wave = tid >> 6;      // 0..15
    const int l15 = lane & 15;
    const int lq = lane >> 4;
    const int r7s = (l15 & 7) << 3; // read-side swizzle (ushort units)

    const int ntiles = (n + 15) >> 4;
    const int tstride = 256 * 16;

    for (int tile = blockIdx.x * 16 + wave; tile < ntiles; tile += tstride) {
        const int wb = tile * 16;
        f32x4 acc[4];
        #pragma unroll
        for (int t = 0; t < 4; t++) acc[t] = (f32x4){0.f, 0.f, 0.f, 0.f};

        const int arow = min(wb + l15, n - 1);
        const float* xr = x + (size_t)arow * 512;

        #pragma unroll 1
        for (int p = 0; p < 4; p++) {
            #pragma unroll
            for (int step = 0; step < 4; step++) {
                int kloc = step * 32 + lq * 8;
                int kb = p * 128 + kloc;
                float4 v0 = *(const float4*)&xr[kb];
                float4 v1 = *(const float4*)&xr[kb + 4];
                float xf[8] = {v0.x, v0.y, v0.z, v0.w, v1.x, v1.y, v1.z, v1.w};
                bfrag ah, al;
                #pragma unroll
                for (int j = 0; j < 8; j++) {
                    unsigned short hi = f2bf(xf[j]);
                    float rem = xf[j] - bf2f(hi);
                    ah[j] = (short)hi;
                    al[j] = (short)f2bf(rem);
                }
                #pragma unroll
                for (int t = 0; t < 4; t++) {
                    int nrow = t * 16 + l15;
                    int bidx = ((p * 64 + nrow) * 128 + kloc) ^ r7s;
                    bfrag bh = *(const bfrag*)&Wh[bidx];
                    bfrag bl = *(const bfrag*)&Wl[bidx];
                    acc[t] = __builtin_amdgcn_mfma_f32_16x16x32_bf16(al, bh, acc[t], 0, 0, 0);
                    acc[t] = __builtin_amdgcn_mfma_f32_16x16x32_bf16(ah, bl, acc[t], 0, 0, 0);
                    acc[t] = __builtin_amdgcn_mfma_f32_16x16x32_bf16(ah, bh, acc[t], 0, 0, 0);
                }
            }
        }
        // ---- h1b write (bf16 rows, 128 B line-aligned) ----
        #pragma unroll
        for (int t = 0; t < 4; t++) {
            #pragma unroll
            for (int reg = 0; reg < 4; reg++) {
                int grow = wb + lq * 4 + reg;
                if (grow < n) h1b[(size_t)grow * 64 + t * 16 + l15] = f2bf(acc[t][reg]);
            }
        }
        // ---- attention coefficients from fp32 accumulators ----
        const int j7 = l15 & 7;
        const int wrow = wb + lq * 4 + (j7 & 3);
        #pragma unroll
        for (int t = 0; t < 4; t++) {
            int cidx = t * 16 + l15;
            float cs = a_src1[cidx];
            float cd = a_dst1[cidx];
            float ps0 = acc[t][0] * cs, ps1 = acc[t][1] * cs;
            float ps2 = acc[t][2] * cs, ps3 = acc[t][3] * cs;
            float pd0 = acc[t][0] * cd, pd1 = acc[t][1] * cd;
            float pd2 = acc[t][2] * cd, pd3 = acc[t][3] * cd;
            #pragma unroll
            for (int off = 1; off < 8; off <<= 1) {
                ps0 += __shfl_xor(ps0, off);
                ps1 += __shfl_xor(ps1, off);
                ps2 += __shfl_xor(ps2, off);
                ps3 += __shfl_xor(ps3, off);
                pd0 += __shfl_xor(pd0, off);
                pd1 += __shfl_xor(pd1, off);
                pd2 += __shfl_xor(pd2, off);
                pd3 += __shfl_xor(pd3, off);
            }
            int h = (t << 1) | (l15 >> 3);
            if (wrow < n) {
                if (j7 < 4) {
                    float sv = j7 == 0 ? ps0 : j7 == 1 ? ps1 : j7 == 2 ? ps2 : ps3;
                    as1[wrow * 8 + h] = sv;
                } else {
                    float dv = j7 == 4 ? pd0 : j7 == 5 ? pd1 : j7 == 6 ? pd2 : pd3;
                    ad1[wrow * 8 + h] = dv;
                }
            }
        }
    }
}

// ============ K5: per-bucket CSR finalize (packed ebuf) ============
__global__ __launch_bounds__(256) void finalize_kernel(
    const int* __restrict__ boff, const int* __restrict__ ebuf,
    int* __restrict__ csr_off, int* __restrict__ col, int N, int NB) {
    int tid = threadIdx.x;
    int b = blockIdx.x;
    __shared__ int cnt[256];
    __shared__ int cur[256];
    __shared__ int sc[256];
    cnt[tid] = 0;
    __syncthreads();
    int st = boff[b], en = boff[b + 1];
    for (int i = st + tid; i < en; i += 256)
        atomicAdd(&cnt[ebuf[i] & 255], 1);
    __syncthreads();
    int v = cnt[tid];
    sc[tid] = v;
    __syncthreads();
    for (int off = 1; off < 256; off <<= 1) {
        int tv = (tid >= off) ? sc[tid - off] : 0;
        __syncthreads();
        sc[tid] += tv;
        __syncthreads();
    }
    int dbase = b << 8;
    int nd = min(256, N - dbase);
    int o = st + sc[tid] - v;   // exclusive
    if (tid < nd) {
        csr_off[dbase + tid] = o;
        cur[tid] = o;
    }
    __syncthreads();
    for (int i = st + tid; i < en; i += 256) {
        int p = ebuf[i];
        int r = atomicAdd(&cur[p & 255], 1);
        col[r] = ((unsigned int)p) >> 8;
    }
}

// ============ agg1 + fused lin2 ============
__global__ __launch_bounds__(256) void agg1_kernel(
    const int* __restrict__ csr_off, const int* __restrict__ col,
    const ushort_t* __restrict__ h1b, const float* __restrict__ as1,
    const float* __restrict__ ad1,
    const float* __restrict__ b1, const float* __restrict__ W2,
    const float* __restrict__ a_src2, const float* __restrict__ a_dst2,
    float* __restrict__ g2, float* __restrict__ ad2, int n) {
    int d = blockIdx.x * 8 + (threadIdx.x >> 5);
    if (d >= n) return;
    int c = threadIdx.x & 31;
    int hd = c >> 2;
    const ushort_t* myrow = h1b + (size_t)d * 64;
    float adh = ad1[d * 8 + hd];
    float asd = as1[d * 8 + hd];
    float p0 = __expf(lrelu(asd + adh));
    unsigned int u = *(const unsigned int*)(myrow + c * 2);
    float denom = p0;
    float acc0 = p0 * u2lo(u);
    float acc1 = p0 * u2hi(u);
    int st = csr_off[d], en = csr_off[d + 1];
    int e = st;
    for (; e + 4 <= en; e += 4) {
        int s0 = col[e], s1 = col[e + 1], s2 = col[e + 2], s3 = col[e + 3];
        const ushort_t* r0 = h1b + (size_t)s0 * 64;
        const ushort_t* r1 = h1b + (size_t)s1 * 64;
        const ushort_t* r2 = h1b + (size_t)s2 * 64;
        const ushort_t* r3 = h1b + (size_t)s3 * 64;
        float a0 = as1[s0 * 8 + hd];
        float a1 = as1[s1 * 8 + hd];
        float a2 = as1[s2 * 8 + hd];
        float a3 = as1[s3 * 8 + hd];
        unsigned int u0 = *(const unsigned int*)(r0 + c * 2);
        unsigned int u1 = *(const unsigned int*)(r1 + c * 2);
        unsigned int u2 = *(const unsigned int*)(r2 + c * 2);
        unsigned int u3 = *(const unsigned int*)(r3 + c * 2);
        float q0 = __expf(lrelu(a0 + adh));
        float q1 = __expf(lrelu(a1 + adh));
        float q2 = __expf(lrelu(a2 + adh));
        float q3 = __expf(lrelu(a3 + adh));
        denom += (q0 + q1) + (q2 + q3);
        acc0 = fmaf(q0, u2lo(u0), acc0);
        acc1 = fmaf(q0, u2hi(u0), acc1);
        acc0 = fmaf(q1, u2lo(u1), acc0);
        acc1 = fmaf(q1, u2hi(u1), acc1);
        acc0 = fmaf(q2, u2lo(u2), acc0);
        acc1 = fmaf(q2, u2hi(u2), acc1);
        acc0 = fmaf(q3, u2lo(u3), acc0);
        acc1 = fmaf(q3, u2hi(u3), acc1);
    }
    for (; e < en; ++e) {
        int s0 = col[e];
        const ushort_t* r0 = h1b + (size_t)s0 * 64;
        float a0 = as1[s0 * 8 + hd];
        unsigned int u0 = *(const unsigned int*)(r0 + c * 2);
        float q0 = __expf(lrelu(a0 + adh));
        denom += q0;
        acc0 = fmaf(q0, u2lo(u0), acc0);
        acc1 = fmaf(q0, u2hi(u0), acc1);
    }
    float v0 = acc0 / denom + b1[2 * c];
    float v1 = acc1 / denom + b1[2 * c + 1];
    float h0 = v0 > 0.f ? v0 : (__expf(v0) - 1.f);
    float h1v = v1 > 0.f ? v1 : (__expf(v1) - 1.f);
    float g[7];
    #pragma unroll
    for (int j = 0; j < 7; j++) {
        float t = fmaf(h0, W2[(2 * c) * 7 + j], h1v * W2[(2 * c + 1) * 7 + j]);
        #pragma unroll
        for (int off = 1; off < 32; off <<= 1) t += __shfl_xor(t, off);
        g[j] = t;
    }
    float sa = 0.f, da = 0.f;
    #pragma unroll
    for (int j = 0; j < 7; j++) {
        sa = fmaf(g[j], a_src2[j], sa);
        da = fmaf(g[j], a_dst2[j], da);
    }
    if (c < 7) g2[(size_t)d * 8 + c] = g[c];
    if (c == 7) g2[(size_t)d * 8 + 7] = sa;
    if (c == 8) ad2[d] = da;
}

// ============ agg2 + log_softmax ============
__global__ __launch_bounds__(256) void agg2_kernel(
    const int* __restrict__ csr_off, const int* __restrict__ col,
    const float* __restrict__ ad2, const float* __restrict__ g2,
    const float* __restrict__ b2, float* __restrict__ out, int n) {
    int d = blockIdx.x * 4 + (threadIdx.x >> 6);
    if (d >= n) return;
    int lane = threadIdx.x & 63;
    int j = lane >> 3, cc = lane & 7;
    int bl = lane | 7;
    float adv = ad2[d];
    float vd = g2[(size_t)d * 8 + cc];
    float as2d = __shfl(vd, bl);
    float pd = (j == 0) ? __expf(lrelu(as2d + adv)) : 0.f;
    float denom = pd;
    float acc = pd * vd;
    int st = csr_off[d], en = csr_off[d + 1];
    for (int base = st; base < en; base += 8) {
        int eidx = base + j;
        bool valid = eidx < en;
        int s = valid ? col[eidx] : d;
        float val = g2[(size_t)s * 8 + cc];
        float as2s = __shfl(val, bl);
        float p = valid ? __expf(lrelu(as2s + adv)) : 0.f;
        denom += p;
        acc = fmaf(p, val, acc);
    }
    #pragma unroll
    for (int off = 8; off < 64; off <<= 1) {
        acc += __shfl_xor(acc, off);
        denom += __shfl_xor(denom, off);
    }
    float o = acc / denom + ((cc < 7) ? b2[cc] : 0.f);
    float m = (cc < 7) ? o : -1e30f;
    #pragma unroll
    for (int off = 1; off < 8; off <<= 1) m = fmaxf(m, __shfl_xor(m, off));
    float se = (cc < 7) ? __expf(o - m) : 0.f;
    #pragma unroll
    for (int off = 1; off < 8; off <<= 1) se += __shfl_xor(se, off);
    float lse = m + __logf(se);
    if (j == 0 && cc < 7) out[(size_t)d * 7 + cc] = o - lse;
}

extern "C" void kernel_launch(void* const* d_in, const int* in_sizes, int n_in,
                              void* d_out, int out_size, void* d_ws, size_t ws_size,
                              hipStream_t stream) {
    const float* x      = (const float*)d_in[0];
    const int*   ei     = (const int*)d_in[1];
    const float* W1     = (const float*)d_in[2];
    const float* a_src1 = (const float*)d_in[3];
    const float* a_dst1 = (const float*)d_in[4];
    const float* b1     = (const float*)d_in[5];
    const float* W2     = (const float*)d_in[6];
    const float* a_src2 = (const float*)d_in[7];
    const float* a_dst2 = (const float*)d_in[8];
    const float* b2     = (const float*)d_in[9];

    int N = in_sizes[0] / 512;
    int E = in_sizes[1] / 2;
    const int* esrc = ei;
    const int* edst = ei + E;
    int NB = (N + 255) >> 8;   // 391 dst-buckets of 256 nodes

    char* ws = (char*)d_ws;
    size_t off = 0;
    auto alloc = [&](size_t bytes) -> void* {
        void* p = ws + off;
        off += (bytes + 255) & ~(size_t)255;
        return p;
    };
    ushort_t* h1b  = (ushort_t*)alloc((size_t)N * 64 * 2);   // 128 B/row, line-aligned
    float* as1     = (float*)alloc((size_t)N * 8 * 4);
    float* ad1     = (float*)alloc((size_t)N * 8 * 4);
    float* g2      = (float*)alloc((size_t)N * 8 * 4);
    float* ad2     = (float*)alloc((size_t)N * 4);
    int*   csr_off = (int*)alloc((size_t)(N + 1) * 4);
    int*   col     = (int*)alloc((size_t)E * 4);
    int*   ebuf    = (int*)alloc((size_t)E * 4);             // packed (src<<8)|dloc
    ushort_t* Whi  = (ushort_t*)alloc(512 * 64 * 2);
    ushort_t* Wlo  = (ushort_t*)alloc(512 * 64 * 2);
    int*   cnt2d   = (int*)alloc((size_t)NB * SBK * 4);      // per-bucket per-chunk
    int*   bcnt    = (int*)alloc((size_t)NB * 4);
    int*   boff    = (int*)alloc((size_t)(NB + 1) * 4);

    hist_prep_kernel<<<128 + SBK, 256, 0, stream>>>(edst, cnt2d, E, NB, W1, Whi, Wlo);
    scan_cols_kernel<<<NB, 256, 0, stream>>>(cnt2d, bcnt, NB);
    bscan_kernel<<<1, 512, 0, stream>>>(bcnt, boff, csr_off, NB, N, E);
    scatter_kernel<<<SBK, 1024, 0, stream>>>(esrc, edst, boff, cnt2d, ebuf, E, NB);
    gemm_kernel<<<256, 1024, 0, stream>>>(x, Whi, Wlo, h1b, N,
                                          a_src1, a_dst1, as1, ad1);
    finalize_kernel<<<NB, 256, 0, stream>>>(boff, ebuf, csr_off, col, N, NB);
    agg1_kernel<<<(N + 7) / 8, 256, 0, stream>>>(csr_off, col, h1b, as1, ad1, b1,
                                                 W2, a_src2, a_dst2, g2, ad2, N);
    agg2_kernel<<<(N + 3) / 4, 256, 0, stream>>>(csr_off, col, ad2, g2, b2,
                                                 (float*)d_out, N);
}

// Round 10
// 455.720 us; speedup vs baseline: 1.8522x; 1.0175x over previous
//
#include <hip/hip_runtime.h>
#include <hip/hip_bf16.h>

#define NEG_SLOPE 0.2f
#define SBK 256         // scatter chunks (= hist chunks = scatter blocks)

typedef __attribute__((ext_vector_type(8))) short bfrag;
typedef __attribute__((ext_vector_type(4))) float f32x4;
typedef unsigned short ushort_t;

__device__ __forceinline__ float lrelu(float x) {
    return x >= 0.0f ? x : NEG_SLOPE * x;
}
__device__ __forceinline__ unsigned short f2bf(float f) {  // round-to-nearest-even
    unsigned int u = __float_as_uint(f);
    u += 0x7fffu + ((u >> 16) & 1u);
    return (unsigned short)(u >> 16);
}
__device__ __forceinline__ float bf2f(unsigned short h) {
    return __uint_as_float(((unsigned int)h) << 16);
}
__device__ __forceinline__ float u2lo(unsigned int u) {
    return __uint_as_float(u << 16);
}
__device__ __forceinline__ float u2hi(unsigned int u) {
    return __uint_as_float(u & 0xffff0000u);
}

// ============ K1: per-chunk bucket histograms + W1 split-bf16 prep ============
__global__ __launch_bounds__(256) void hist_prep_kernel(
    const int* __restrict__ edst, int* __restrict__ cnt2d, int E, int NB,
    const float* __restrict__ W1, ushort_t* __restrict__ Whi,
    ushort_t* __restrict__ Wlo) {
    if (blockIdx.x < 128) {
        int t = blockIdx.x * 256 + threadIdx.x;  // 32768
        int k = t >> 6, c = t & 63;
        float w = W1[t];
        unsigned short hi = f2bf(w);
        float rem = w - bf2f(hi);
        int dst = (k >> 7) * 8192 + c * 128 + (k & 127);
        Whi[dst] = hi;
        Wlo[dst] = f2bf(rem);
        return;
    }
    __shared__ int hist[512];
    int tid = threadIdx.x;
    for (int i = tid; i < 512; i += 256) hist[i] = 0;
    __syncthreads();
    int s = blockIdx.x - 128;           // chunk id 0..SBK-1
    int CH = (E + SBK - 1) / SBK;
    int st = s * CH, en = min(st + CH, E);
    for (int i = st + tid; i < en; i += 256)
        atomicAdd(&hist[edst[i] >> 8], 1);
    __syncthreads();
    for (int b = tid; b < NB; b += 256)
        cnt2d[b * SBK + s] = hist[b];
}

// ============ K2a: per-bucket exclusive scan over chunks ============
__global__ __launch_bounds__(256) void scan_cols_kernel(
    int* __restrict__ cnt2d, int* __restrict__ bcnt, int NB) {
    int b = blockIdx.x;
    int t = threadIdx.x;
    __shared__ int sc[256];
    int v = cnt2d[b * SBK + t];
    sc[t] = v;
    __syncthreads();
    for (int off = 1; off < 256; off <<= 1) {
        int tv = (t >= off) ? sc[t - off] : 0;
        __syncthreads();
        sc[t] += tv;
        __syncthreads();
    }
    cnt2d[b * SBK + t] = sc[t] - v;   // exclusive prefix within bucket
    if (t == 255) bcnt[b] = sc[255];
}

// ============ K2b: bucket exclusive scan (one WG) ============
__global__ __launch_bounds__(512) void bscan_kernel(
    const int* __restrict__ bcnt, int* __restrict__ boff,
    int* __restrict__ csr_off, int NB, int N, int E) {
    __shared__ int s[512];
    int t = threadIdx.x;
    int v = (t < NB) ? bcnt[t] : 0;
    s[t] = v;
    __syncthreads();
    for (int off = 1; off < 512; off <<= 1) {
        int tv = (t >= off) ? s[t - off] : 0;
        __syncthreads();
        s[t] += tv;
        __syncthreads();
    }
    if (t < NB) boff[t] = s[t] - v;
    if (t == 0) {
        boff[NB] = E;
        csr_off[N] = E;
    }
}

// ============ K3: bucket scatter — ZERO global atomics ============
__global__ __launch_bounds__(1024) void scatter_kernel(
    const int* __restrict__ esrc, const int* __restrict__ edst,
    const int* __restrict__ boff, const int* __restrict__ cnt2d,
    int* __restrict__ ebuf, int E, int NB) {
    __shared__ int base[512];
    __shared__ int rank[512];
    int tid = threadIdx.x;
    int s = blockIdx.x;
    for (int b = tid; b < NB; b += 1024) {
        base[b] = boff[b] + cnt2d[b * SBK + s];
        rank[b] = 0;
    }
    __syncthreads();
    int CH = (E + SBK - 1) / SBK;
    int st = s * CH, en = min(st + CH, E);
    for (int i = st + tid; i < en; i += 1024) {
        int d = edst[i];
        int b = d >> 8;
        int r = atomicAdd(&rank[b], 1);
        ebuf[base[b] + r] = (esrc[i] << 8) | (d & 255);
    }
}

// ============ K4: GEMM1 + attention coeffs — 2 tiles/wave, 1 round ============
// 256 blocks x 1024 threads. W (hi+lo, 128 KB) staged once into LDS
// (XOR-swizzled). Each wave owns TWO 16-row tiles (32 rows): B-fragments
// shared between tiles (halves LDS reads), x-load ILP doubled, and 3125
// pair-tasks < 4096 wave-slots -> single-round makespan.
__global__ __launch_bounds__(1024, 4) void gemm_kernel(
    const float* __restrict__ x, const ushort_t* __restrict__ Whi,
    const ushort_t* __restrict__ Wlo, ushort_t* __restrict__ h1b, int n,
    const float* __restrict__ a_src1, const float* __restrict__ a_dst1,
    float* __restrict__ as1, float* __restrict__ ad1) {
    __shared__ __align__(16) ushort_t Wh[32768];   // 64 KB swizzled
    __shared__ __align__(16) ushort_t Wl[32768];   // 64 KB
    const int tid = threadIdx.x;   // 0..1023

    #pragma unroll
    for (int i = 0; i < 4; i++) {
        int lin = (tid + i * 1024) * 8;
        int row = (lin >> 7) & 63;
        int swz = lin ^ ((row & 7) << 3);
        *(bfrag*)&Wh[swz] = *(const bfrag*)&Whi[lin];
        *(bfrag*)&Wl[swz] = *(const bfrag*)&Wlo[lin];
    }
    __syncthreads();

    const int lane = tid & 63;
    const int wave = tid >> 6;      // 0..15
    const int l15 = lane & 15;
    const int lq = lane >> 4;
    const int r7s = (l15 & 7) << 3; // read-side swizzle (ushort units)

    const int ntiles = (n + 15) >> 4;
    const int npairs = (ntiles + 1) >> 1;
    const int pstride = 256 * 16;

    for (int pair = blockIdx.x * 16 + wave; pair < npairs; pair += pstride) {
        const int wb = pair * 32;
        f32x4 acc0[4], acc1[4];
        #pragma unroll
        for (int t = 0; t < 4; t++) {
            acc0[t] = (f32x4){0.f, 0.f, 0.f, 0.f};
            acc1[t] = (f32x4){0.f, 0.f, 0.f, 0.f};
        }

        const int ar0 = min(wb + l15, n - 1);
        const int ar1 = min(wb + 16 + l15, n - 1);
        const float* xr0 = x + (size_t)ar0 * 512;
        const float* xr1 = x + (size_t)ar1 * 512;

        #pragma unroll 1
        for (int p = 0; p < 4; p++) {
            #pragma unroll
            for (int step = 0; step < 4; step++) {
                int kloc = step * 32 + lq * 8;
                int kb = p * 128 + kloc;
                float4 a0 = *(const float4*)&xr0[kb];
                float4 a1 = *(const float4*)&xr0[kb + 4];
                float4 b0 = *(const float4*)&xr1[kb];
                float4 b1v = *(const float4*)&xr1[kb + 4];
                float xf0[8] = {a0.x, a0.y, a0.z, a0.w, a1.x, a1.y, a1.z, a1.w};
                float xf1[8] = {b0.x, b0.y, b0.z, b0.w, b1v.x, b1v.y, b1v.z, b1v.w};
                bfrag ah0, al0, ah1, al1;
                #pragma unroll
                for (int j = 0; j < 8; j++) {
                    unsigned short h0 = f2bf(xf0[j]);
                    al0[j] = (short)f2bf(xf0[j] - bf2f(h0));
                    ah0[j] = (short)h0;
                    unsigned short h1 = f2bf(xf1[j]);
                    al1[j] = (short)f2bf(xf1[j] - bf2f(h1));
                    ah1[j] = (short)h1;
                }
                #pragma unroll
                for (int t = 0; t < 4; t++) {
                    int nrow = t * 16 + l15;
                    int bidx = ((p * 64 + nrow) * 128 + kloc) ^ r7s;
                    bfrag bh = *(const bfrag*)&Wh[bidx];
                    bfrag bl = *(const bfrag*)&Wl[bidx];
                    acc0[t] = __builtin_amdgcn_mfma_f32_16x16x32_bf16(al0, bh, acc0[t], 0, 0, 0);
                    acc0[t] = __builtin_amdgcn_mfma_f32_16x16x32_bf16(ah0, bl, acc0[t], 0, 0, 0);
                    acc0[t] = __builtin_amdgcn_mfma_f32_16x16x32_bf16(ah0, bh, acc0[t], 0, 0, 0);
                    acc1[t] = __builtin_amdgcn_mfma_f32_16x16x32_bf16(al1, bh, acc1[t], 0, 0, 0);
                    acc1[t] = __builtin_amdgcn_mfma_f32_16x16x32_bf16(ah1, bl, acc1[t], 0, 0, 0);
                    acc1[t] = __builtin_amdgcn_mfma_f32_16x16x32_bf16(ah1, bh, acc1[t], 0, 0, 0);
                }
            }
        }
        // ---- epilogue for both tiles ----
        #pragma unroll
        for (int half = 0; half < 2; half++) {
            const f32x4* acc = half ? acc1 : acc0;
            const int tb = wb + half * 16;
            #pragma unroll
            for (int t = 0; t < 4; t++) {
                #pragma unroll
                for (int reg = 0; reg < 4; reg++) {
                    int grow = tb + lq * 4 + reg;
                    if (grow < n) h1b[(size_t)grow * 64 + t * 16 + l15] = f2bf(acc[t][reg]);
                }
            }
            const int j7 = l15 & 7;
            const int wrow = tb + lq * 4 + (j7 & 3);
            #pragma unroll
            for (int t = 0; t < 4; t++) {
                int cidx = t * 16 + l15;
                float cs = a_src1[cidx];
                float cd = a_dst1[cidx];
                float ps0 = acc[t][0] * cs, ps1 = acc[t][1] * cs;
                float ps2 = acc[t][2] * cs, ps3 = acc[t][3] * cs;
                float pd0 = acc[t][0] * cd, pd1 = acc[t][1] * cd;
                float pd2 = acc[t][2] * cd, pd3 = acc[t][3] * cd;
                #pragma unroll
                for (int off = 1; off < 8; off <<= 1) {
                    ps0 += __shfl_xor(ps0, off);
                    ps1 += __shfl_xor(ps1, off);
                    ps2 += __shfl_xor(ps2, off);
                    ps3 += __shfl_xor(ps3, off);
                    pd0 += __shfl_xor(pd0, off);
                    pd1 += __shfl_xor(pd1, off);
                    pd2 += __shfl_xor(pd2, off);
                    pd3 += __shfl_xor(pd3, off);
                }
                int h = (t << 1) | (l15 >> 3);
                if (wrow < n) {
                    if (j7 < 4) {
                        float sv = j7 == 0 ? ps0 : j7 == 1 ? ps1 : j7 == 2 ? ps2 : ps3;
                        as1[wrow * 8 + h] = sv;
                    } else {
                        float dv = j7 == 4 ? pd0 : j7 == 5 ? pd1 : j7 == 6 ? pd2 : pd3;
                        ad1[wrow * 8 + h] = dv;
                    }
                }
            }
        }
    }
}

// ============ K5: per-bucket CSR finalize (packed ebuf) ============
__global__ __launch_bounds__(256) void finalize_kernel(
    const int* __restrict__ boff, const int* __restrict__ ebuf,
    int* __restrict__ csr_off, int* __restrict__ col, int N, int NB) {
    int tid = threadIdx.x;
    int b = blockIdx.x;
    __shared__ int cnt[256];
    __shared__ int cur[256];
    __shared__ int sc[256];
    cnt[tid] = 0;
    __syncthreads();
    int st = boff[b], en = boff[b + 1];
    for (int i = st + tid; i < en; i += 256)
        atomicAdd(&cnt[ebuf[i] & 255], 1);
    __syncthreads();
    int v = cnt[tid];
    sc[tid] = v;
    __syncthreads();
    for (int off = 1; off < 256; off <<= 1) {
        int tv = (tid >= off) ? sc[tid - off] : 0;
        __syncthreads();
        sc[tid] += tv;
        __syncthreads();
    }
    int dbase = b << 8;
    int nd = min(256, N - dbase);
    int o = st + sc[tid] - v;   // exclusive
    if (tid < nd) {
        csr_off[dbase + tid] = o;
        cur[tid] = o;
    }
    __syncthreads();
    for (int i = st + tid; i < en; i += 256) {
        int p = ebuf[i];
        int r = atomicAdd(&cur[p & 255], 1);
        col[r] = ((unsigned int)p) >> 8;
    }
}

// ============ agg1 + fused lin2 — 16 lanes/dst (2x gather ILP) ============
__global__ __launch_bounds__(256) void agg1_kernel(
    const int* __restrict__ csr_off, const int* __restrict__ col,
    const ushort_t* __restrict__ h1b, const float* __restrict__ as1,
    const float* __restrict__ ad1,
    const float* __restrict__ b1, const float* __restrict__ W2,
    const float* __restrict__ a_src2, const float* __restrict__ a_dst2,
    float* __restrict__ g2, float* __restrict__ ad2, int n) {
    int d = blockIdx.x * 16 + (threadIdx.x >> 4);
    if (d >= n) return;
    int c16 = threadIdx.x & 15;         // lane owns features 4*c16 .. 4*c16+3
    int hd = c16 >> 1;                  // head of those features
    const ushort_t* myrow = h1b + (size_t)d * 64;
    float adh = ad1[d * 8 + hd];
    float asd = as1[d * 8 + hd];
    float p0 = __expf(lrelu(asd + adh));
    uint2 uu = *(const uint2*)(myrow + c16 * 4);
    float denom = p0;
    float acc0 = p0 * u2lo(uu.x);
    float acc1 = p0 * u2hi(uu.x);
    float acc2 = p0 * u2lo(uu.y);
    float acc3 = p0 * u2hi(uu.y);
    int st = csr_off[d], en = csr_off[d + 1];
    int e = st;
    for (; e + 4 <= en; e += 4) {
        int s0 = col[e], s1 = col[e + 1], s2 = col[e + 2], s3 = col[e + 3];
        const ushort_t* r0 = h1b + (size_t)s0 * 64;
        const ushort_t* r1 = h1b + (size_t)s1 * 64;
        const ushort_t* r2 = h1b + (size_t)s2 * 64;
        const ushort_t* r3 = h1b + (size_t)s3 * 64;
        float a0 = as1[s0 * 8 + hd];
        float a1 = as1[s1 * 8 + hd];
        float a2 = as1[s2 * 8 + hd];
        float a3 = as1[s3 * 8 + hd];
        uint2 u0 = *(const uint2*)(r0 + c16 * 4);
        uint2 u1 = *(const uint2*)(r1 + c16 * 4);
        uint2 u2 = *(const uint2*)(r2 + c16 * 4);
        uint2 u3 = *(const uint2*)(r3 + c16 * 4);
        float q0 = __expf(lrelu(a0 + adh));
        float q1 = __expf(lrelu(a1 + adh));
        float q2 = __expf(lrelu(a2 + adh));
        float q3 = __expf(lrelu(a3 + adh));
        denom += (q0 + q1) + (q2 + q3);
        acc0 = fmaf(q0, u2lo(u0.x), acc0);
        acc1 = fmaf(q0, u2hi(u0.x), acc1);
        acc2 = fmaf(q0, u2lo(u0.y), acc2);
        acc3 = fmaf(q0, u2hi(u0.y), acc3);
        acc0 = fmaf(q1, u2lo(u1.x), acc0);
        acc1 = fmaf(q1, u2hi(u1.x), acc1);
        acc2 = fmaf(q1, u2lo(u1.y), acc2);
        acc3 = fmaf(q1, u2hi(u1.y), acc3);
        acc0 = fmaf(q2, u2lo(u2.x), acc0);
        acc1 = fmaf(q2, u2hi(u2.x), acc1);
        acc2 = fmaf(q2, u2lo(u2.y), acc2);
        acc3 = fmaf(q2, u2hi(u2.y), acc3);
        acc0 = fmaf(q3, u2lo(u3.x), acc0);
        acc1 = fmaf(q3, u2hi(u3.x), acc1);
        acc2 = fmaf(q3, u2lo(u3.y), acc2);
        acc3 = fmaf(q3, u2hi(u3.y), acc3);
    }
    for (; e < en; ++e) {
        int s0 = col[e];
        const ushort_t* r0 = h1b + (size_t)s0 * 64;
        float a0 = as1[s0 * 8 + hd];
        uint2 u0 = *(const uint2*)(r0 + c16 * 4);
        float q0 = __expf(lrelu(a0 + adh));
        denom += q0;
        acc0 = fmaf(q0, u2lo(u0.x), acc0);
        acc1 = fmaf(q0, u2hi(u0.x), acc1);
        acc2 = fmaf(q0, u2lo(u0.y), acc2);
        acc3 = fmaf(q0, u2hi(u0.y), acc3);
    }
    int f0 = c16 * 4;
    float v0 = acc0 / denom + b1[f0];
    float v1 = acc1 / denom + b1[f0 + 1];
    float v2 = acc2 / denom + b1[f0 + 2];
    float v3 = acc3 / denom + b1[f0 + 3];
    float h0 = v0 > 0.f ? v0 : (__expf(v0) - 1.f);
    float h1 = v1 > 0.f ? v1 : (__expf(v1) - 1.f);
    float h2 = v2 > 0.f ? v2 : (__expf(v2) - 1.f);
    float h3 = v3 > 0.f ? v3 : (__expf(v3) - 1.f);
    float g[7];
    #pragma unroll
    for (int j = 0; j < 7; j++) {
        float t = h0 * W2[f0 * 7 + j];
        t = fmaf(h1, W2[(f0 + 1) * 7 + j], t);
        t = fmaf(h2, W2[(f0 + 2) * 7 + j], t);
        t = fmaf(h3, W2[(f0 + 3) * 7 + j], t);
        #pragma unroll
        for (int off = 1; off < 16; off <<= 1) t += __shfl_xor(t, off);
        g[j] = t;
    }
    float sa = 0.f, da = 0.f;
    #pragma unroll
    for (int j = 0; j < 7; j++) {
        sa = fmaf(g[j], a_src2[j], sa);
        da = fmaf(g[j], a_dst2[j], da);
    }
    if (c16 < 7) g2[(size_t)d * 8 + c16] = g[c16];
    if (c16 == 7) g2[(size_t)d * 8 + 7] = sa;
    if (c16 == 8) ad2[d] = da;
}

// ============ agg2 + log_softmax ============
__global__ __launch_bounds__(256) void agg2_kernel(
    const int* __restrict__ csr_off, const int* __restrict__ col,
    const float* __restrict__ ad2, const float* __restrict__ g2,
    const float* __restrict__ b2, float* __restrict__ out, int n) {
    int d = blockIdx.x * 4 + (threadIdx.x >> 6);
    if (d >= n) return;
    int lane = threadIdx.x & 63;
    int j = lane >> 3, cc = lane & 7;
    int bl = lane | 7;
    float adv = ad2[d];
    float vd = g2[(size_t)d * 8 + cc];
    float as2d = __shfl(vd, bl);
    float pd = (j == 0) ? __expf(lrelu(as2d + adv)) : 0.f;
    float denom = pd;
    float acc = pd * vd;
    int st = csr_off[d], en = csr_off[d + 1];
    for (int base = st; base < en; base += 8) {
        int eidx = base + j;
        bool valid = eidx < en;
        int s = valid ? col[eidx] : d;
        float val = g2[(size_t)s * 8 + cc];
        float as2s = __shfl(val, bl);
        float p = valid ? __expf(lrelu(as2s + adv)) : 0.f;
        denom += p;
        acc = fmaf(p, val, acc);
    }
    #pragma unroll
    for (int off = 8; off < 64; off <<= 1) {
        acc += __shfl_xor(acc, off);
        denom += __shfl_xor(denom, off);
    }
    float o = acc / denom + ((cc < 7) ? b2[cc] : 0.f);
    float m = (cc < 7) ? o : -1e30f;
    #pragma unroll
    for (int off = 1; off < 8; off <<= 1) m = fmaxf(m, __shfl_xor(m, off));
    float se = (cc < 7) ? __expf(o - m) : 0.f;
    #pragma unroll
    for (int off = 1; off < 8; off <<= 1) se += __shfl_xor(se, off);
    float lse = m + __logf(se);
    if (j == 0 && cc < 7) out[(size_t)d * 7 + cc] = o - lse;
}

extern "C" void kernel_launch(void* const* d_in, const int* in_sizes, int n_in,
                              void* d_out, int out_size, void* d_ws, size_t ws_size,
                              hipStream_t stream) {
    const float* x      = (const float*)d_in[0];
    const int*   ei     = (const int*)d_in[1];
    const float* W1     = (const float*)d_in[2];
    const float* a_src1 = (const float*)d_in[3];
    const float* a_dst1 = (const float*)d_in[4];
    const float* b1     = (const float*)d_in[5];
    const float* W2     = (const float*)d_in[6];
    const float* a_src2 = (const float*)d_in[7];
    const float* a_dst2 = (const float*)d_in[8];
    const float* b2     = (const float*)d_in[9];

    int N = in_sizes[0] / 512;
    int E = in_sizes[1] / 2;
    const int* esrc = ei;
    const int* edst = ei + E;
    int NB = (N + 255) >> 8;   // 391 dst-buckets of 256 nodes

    char* ws = (char*)d_ws;
    size_t off = 0;
    auto alloc = [&](size_t bytes) -> void* {
        void* p = ws + off;
        off += (bytes + 255) & ~(size_t)255;
        return p;
    };
    ushort_t* h1b  = (ushort_t*)alloc((size_t)N * 64 * 2);   // 128 B/row, line-aligned
    float* as1     = (float*)alloc((size_t)N * 8 * 4);
    float* ad1     = (float*)alloc((size_t)N * 8 * 4);
    float* g2      = (float*)alloc((size_t)N * 8 * 4);
    float* ad2     = (float*)alloc((size_t)N * 4);
    int*   csr_off = (int*)alloc((size_t)(N + 1) * 4);
    int*   col     = (int*)alloc((size_t)E * 4);
    int*   ebuf    = (int*)alloc((size_t)E * 4);             // packed (src<<8)|dloc
    ushort_t* Whi  = (ushort_t*)alloc(512 * 64 * 2);
    ushort_t* Wlo  = (ushort_t*)alloc(512 * 64 * 2);
    int*   cnt2d   = (int*)alloc((size_t)NB * SBK * 4);      // per-bucket per-chunk
    int*   bcnt    = (int*)alloc((size_t)NB * 4);
    int*   boff    = (int*)alloc((size_t)(NB + 1) * 4);

    hist_prep_kernel<<<128 + SBK, 256, 0, stream>>>(edst, cnt2d, E, NB, W1, Whi, Wlo);
    scan_cols_kernel<<<NB, 256, 0, stream>>>(cnt2d, bcnt, NB);
    bscan_kernel<<<1, 512, 0, stream>>>(bcnt, boff, csr_off, NB, N, E);
    scatter_kernel<<<SBK, 1024, 0, stream>>>(esrc, edst, boff, cnt2d, ebuf, E, NB);
    gemm_kernel<<<256, 1024, 0, stream>>>(x, Whi, Wlo, h1b, N,
                                          a_src1, a_dst1, as1, ad1);
    finalize_kernel<<<NB, 256, 0, stream>>>(boff, ebuf, csr_off, col, N, NB);
    agg1_kernel<<<(N + 15) / 16, 256, 0, stream>>>(csr_off, col, h1b, as1, ad1, b1,
                                                   W2, a_src2, a_dst2, g2, ad2, N);
    agg2_kernel<<<(N + 3) / 4, 256, 0, stream>>>(csr_off, col, ad2, g2, b2,
                                                 (float*)d_out, N);
}